// Round 1
// baseline (215.631 us; speedup 1.0000x reference)
//
#include <hip/hip_runtime.h>

#define B_ 16
#define L_ 32
#define O_ 32
#define M_ 256
#define CH_ 544   // L*(P+1)

// ---------- LAPACK helper transcriptions (f32) ----------

__device__ __forceinline__ float wave_sum64(float v) {
#pragma unroll
  for (int off = 32; off > 0; off >>= 1) v += __shfl_xor(v, off, 64);
  return v;
}

__device__ __forceinline__ float slapy2f(float x, float y) {
  float xa = fabsf(x), ya = fabsf(y);
  float w = fmaxf(xa, ya), z = fminf(xa, ya);
  if (z == 0.f) return w;
  float q = z / w;
  return w * sqrtf(1.f + q * q);
}

// LAPACK >= 3.10 slartg convention (c >= 0, r = sign(f)*hypot).
// (Pre-3.10: c=f/r, s=g/r, r>0 unless |f|>|g| && c<0 -> negate all.)
__device__ __forceinline__ void slartgf(float f, float g, float* c, float* s, float* r) {
  if (g == 0.f) { *c = 1.f; *s = 0.f; *r = f; }
  else if (f == 0.f) { *c = 0.f; *s = copysignf(1.f, g); *r = fabsf(g); }
  else {
    float d = sqrtf(f * f + g * g);
    *c = fabsf(f) / d;
    *r = copysignf(d, f);
    *s = g / *r;
  }
}

__device__ __forceinline__ void slaev2f(float a, float b, float c,
                                        float* rt1, float* rt2, float* cs1, float* sn1) {
  float sm = a + c, df = a - c;
  float adf = fabsf(df);
  float tb = b + b;
  float ab = fabsf(tb);
  float acmx, acmn;
  if (fabsf(a) > fabsf(c)) { acmx = a; acmn = c; } else { acmx = c; acmn = a; }
  float rt;
  if (adf > ab) { float q = ab / adf; rt = adf * sqrtf(1.f + q * q); }
  else if (adf < ab) { float q = adf / ab; rt = ab * sqrtf(1.f + q * q); }
  else rt = ab * sqrtf(2.f);
  int sgn1;
  if (sm < 0.f) { *rt1 = 0.5f * (sm - rt); sgn1 = -1; *rt2 = (acmx / *rt1) * acmn - (b / *rt1) * b; }
  else if (sm > 0.f) { *rt1 = 0.5f * (sm + rt); sgn1 = 1; *rt2 = (acmx / *rt1) * acmn - (b / *rt1) * b; }
  else { *rt1 = 0.5f * rt; *rt2 = -0.5f * rt; sgn1 = 1; }
  float cs; int sgn2;
  if (df >= 0.f) { cs = df + rt; sgn2 = 1; } else { cs = df - rt; sgn2 = -1; }
  float acs = fabsf(cs), c1, s1;
  if (acs > ab) { float ct = -tb / cs; s1 = 1.f / sqrtf(1.f + ct * ct); c1 = ct * s1; }
  else if (ab == 0.f) { c1 = 1.f; s1 = 0.f; }
  else { float tn = -cs / tb; c1 = 1.f / sqrtf(1.f + tn * tn); s1 = tn * c1; }
  if (sgn1 == sgn2) { float tn = c1; c1 = -s1; s1 = tn; }
  *cs1 = c1; *sn1 = s1;
}

// ---------- Kernel 1: weighted pose second moments ----------
// T[b,l][r][c] = sum_m (a*p_r)*(a*p_c), p = flattened 4x4 pose (idx 4i+j)
__global__ __launch_bounds__(256) void moments_kernel(const float* __restrict__ in,
                                                      float* __restrict__ Tmom) {
  int bl = blockIdx.x;
  int b = bl >> 5, l = bl & 31;
  __shared__ float u[64][16];
  __shared__ float ash[64];
  int t = threadIdx.x;
  int r = t >> 4, c = t & 15;
  float acc = 0.f;
  const float* base = in + (size_t)b * (M_ * CH_);
  for (int m0 = 0; m0 < M_; m0 += 64) {
    if (t < 64) ash[t] = base[(m0 + t) * CH_ + 512 + l];
    __syncthreads();
#pragma unroll
    for (int i = 0; i < 4; i++) {
      int idx = i * 256 + t;
      int mm = idx >> 4, j = idx & 15;
      u[mm][j] = ash[mm] * base[(m0 + mm) * CH_ + l * 16 + j];
    }
    __syncthreads();
#pragma unroll 8
    for (int mm = 0; mm < 64; mm++) acc += u[mm][r] * u[mm][c];
    __syncthreads();
  }
  Tmom[bl * 256 + t] = acc;
}

// ---------- Kernel 2: gram via T, then LAPACK-replica eigh, outputs ----------
__global__ __launch_bounds__(256) void gram_eig_kernel(const float* __restrict__ Tmom,
                                                       const float* __restrict__ Wt,
                                                       const float* __restrict__ bias,
                                                       float* __restrict__ out) {
  int bo = blockIdx.x;
  int b = bo >> 5, o = bo & 31;
  int t = threadIdx.x;

  __shared__ float Tsh[256];
  __shared__ float Ush[256];
  __shared__ float Wsh[16];
  __shared__ float A[16][17];
  __shared__ float Zm[16][17];
  __shared__ float dd[16], ee[16], tauv[16], wvec[16];

  int p = t >> 4, q = t & 15;
  int i_ = p >> 2, k_ = p & 3;
  int i2 = q >> 2, k2 = q & 3;

  // G[(i,k),(i',k')] = sum_l sum_{j,j'} T[(i,j),(i',j')] W[l,o,j,k] W[l,o,j',k']
  float g = 0.f;
  for (int l = 0; l < L_; l++) {
    Tsh[t] = Tmom[((b * L_) + l) * 256 + t];
    if (t < 16) Wsh[t] = Wt[((l * O_) + o) * 16 + t];   // W[j][k] at j*4+k
    __syncthreads();
    float uacc = 0.f;
#pragma unroll
    for (int jp = 0; jp < 4; jp++)
      uacc += Tsh[p * 16 + i2 * 4 + jp] * Wsh[jp * 4 + k2];  // U[(i,j)][(i',k')]
    Ush[t] = uacc;
    __syncthreads();
    float gacc = 0.f;
#pragma unroll
    for (int j = 0; j < 4; j++)
      gacc += Wsh[j * 4 + k_] * Ush[(i_ * 4 + j) * 16 + q];
    g += gacc;
    __syncthreads();
  }
  A[p][q] = g;
  Zm[p][q] = (p == q) ? 1.f : 0.f;
  __syncthreads();

  if (t < 64) {
    int lane = t;
    // trace of G (denominator ||Y||_F^2)
    float trace = wave_sum64((lane < 16) ? A[lane][lane] : 0.f);

    // ---- ssytd2 (lower) ----
    for (int i = 0; i < 15; i++) {
      float alpha = A[i + 1][i];
      float xv = (lane >= i + 2 && lane < 16) ? A[lane][i] : 0.f;
      float xn2 = wave_sum64(xv * xv);
      float taui;
      if (xn2 == 0.f) {
        taui = 0.f;
        if (lane == 0) ee[i] = alpha;
      } else {
        float xnorm = sqrtf(xn2);
        float beta = -copysignf(slapy2f(alpha, xnorm), alpha);
        taui = (beta - alpha) / beta;
        float rs = 1.f / (alpha - beta);
        if (lane >= i + 2 && lane < 16) A[lane][i] = xv * rs;
        if (lane == 0) { ee[i] = beta; A[i + 1][i] = 1.f; }
        // w = tau * Asym * v  (v = A[.,i], v[i+1]=1)
        float wr = 0.f;
        if (lane >= i + 1 && lane < 16) {
          for (int c = i + 1; c < 16; c++) {
            float av = (lane >= c) ? A[lane][c] : A[c][lane];
            wr += av * A[c][i];
          }
          wr *= taui;
        }
        float vr = (lane >= i + 1 && lane < 16) ? A[lane][i] : 0.f;
        float dot = wave_sum64(wr * vr);
        float alph2 = -0.5f * taui * dot;
        wr += alph2 * vr;
        if (lane >= i + 1 && lane < 16) wvec[lane] = wr;
        if (lane >= i + 1 && lane < 16) {
          float vl = A[lane][i];
          for (int c = i + 1; c <= lane; c++)
            A[lane][c] -= vl * wvec[c] + wr * A[c][i];
        }
        if (lane == 0) A[i + 1][i] = beta;
      }
      if (lane == 0) { dd[i] = A[i][i]; tauv[i] = taui; }
    }
    if (lane == 0) dd[15] = A[15][15];

    // ---- form Q = H(1)..H(14) into Zm (backward accumulation) ----
    for (int i = 13; i >= 0; i--) {
      float taui = tauv[i];
      if (taui != 0.f && lane < 16) {
        float s = Zm[i + 1][lane];
        for (int r = i + 2; r < 16; r++) s += A[r][i] * Zm[r][lane];
        s *= taui;
        Zm[i + 1][lane] -= s;
        for (int r = i + 2; r < 16; r++) Zm[r][lane] -= A[r][i] * s;
      }
    }

    // ---- ssteqr ----
    const float eps = 5.9604645e-08f;
    const float eps2 = eps * eps;
    const float safmin = 1.17549435e-38f;
    int l1 = 0, jtot = 0;
    const int nmaxit = 480;

    while (l1 < 16) {
      if (l1 > 0) { if (lane == 0) ee[l1 - 1] = 0.f; }
      int m;
      for (m = l1; m < 15; m++) {
        float tst = fabsf(ee[m]);
        if (tst == 0.f) break;
        if (tst <= sqrtf(fabsf(dd[m])) * sqrtf(fabsf(dd[m + 1])) * eps) {
          if (lane == 0) ee[m] = 0.f;
          break;
        }
      }
      int l = l1, lend = m;
      l1 = m + 1;
      if (lend == l) continue;
      if (fabsf(dd[lend]) < fabsf(dd[l])) { int tmp = l; l = lend; lend = tmp; }

      if (lend > l) {
        // QL iteration
        for (;;) {
          int mq;
          if (l != lend) {
            for (mq = l; mq < lend; mq++) {
              float tst = ee[mq] * ee[mq];
              if (tst <= eps2 * fabsf(dd[mq]) * fabsf(dd[mq + 1]) + safmin) break;
            }
          } else mq = lend;
          if (mq < lend) { if (lane == 0) ee[mq] = 0.f; }
          float pp = dd[l];
          if (mq == l) {            // eigenvalue found
            l++;
            if (l <= lend) continue;
            break;
          }
          if (mq == l + 1) {        // 2x2 block
            float rt1, rt2, cc, ss;
            slaev2f(dd[l], ee[l], dd[l + 1], &rt1, &rt2, &cc, &ss);
            if (lane < 16) {
              float z1 = Zm[lane][l + 1], z0 = Zm[lane][l];
              Zm[lane][l + 1] = cc * z1 - ss * z0;
              Zm[lane][l] = ss * z1 + cc * z0;
            }
            if (lane == 0) { dd[l] = rt1; dd[l + 1] = rt2; ee[l] = 0.f; }
            l += 2;
            if (l <= lend) continue;
            break;
          }
          if (jtot == nmaxit) break;
          jtot++;
          float gg = (dd[l + 1] - pp) / (2.f * ee[l]);
          float rr = slapy2f(gg, 1.f);
          gg = dd[mq] - pp + ee[l] / (gg + copysignf(rr, gg));
          float ss_ = 1.f, cc_ = 1.f;
          pp = 0.f;
          for (int i = mq - 1; i >= l; i--) {
            float ff = ss_ * ee[i];
            float bb = cc_ * ee[i];
            slartgf(gg, ff, &cc_, &ss_, &rr);
            if (i != mq - 1) { if (lane == 0) ee[i + 1] = rr; }
            gg = dd[i + 1] - pp;
            rr = (dd[i] - gg) * ss_ + 2.f * cc_ * bb;
            pp = ss_ * rr;
            if (lane == 0) dd[i + 1] = gg + pp;
            gg = cc_ * rr - bb;
            // apply rotation (c, -s) to Z cols (i, i+1); same order as slasr 'B'
            float sj = -ss_;
            if (lane < 16) {
              float z1 = Zm[lane][i + 1], z0 = Zm[lane][i];
              Zm[lane][i + 1] = cc_ * z1 - sj * z0;
              Zm[lane][i] = sj * z1 + cc_ * z0;
            }
          }
          if (lane == 0) { dd[l] = dd[l] - pp; ee[l] = gg; }
        }
      } else {
        // QR iteration
        for (;;) {
          int mq;
          if (l != lend) {
            for (mq = l; mq > lend; mq--) {
              float tst = ee[mq - 1] * ee[mq - 1];
              if (tst <= eps2 * fabsf(dd[mq]) * fabsf(dd[mq - 1]) + safmin) break;
            }
          } else mq = lend;
          if (mq > lend) { if (lane == 0) ee[mq - 1] = 0.f; }
          float pp = dd[l];
          if (mq == l) {
            l--;
            if (l >= lend) continue;
            break;
          }
          if (mq == l - 1) {
            float rt1, rt2, cc, ss;
            slaev2f(dd[l - 1], ee[l - 1], dd[l], &rt1, &rt2, &cc, &ss);
            if (lane < 16) {
              float z1 = Zm[lane][l], z0 = Zm[lane][l - 1];
              Zm[lane][l] = cc * z1 - ss * z0;
              Zm[lane][l - 1] = ss * z1 + cc * z0;
            }
            if (lane == 0) { dd[l - 1] = rt1; dd[l] = rt2; ee[l - 1] = 0.f; }
            l -= 2;
            if (l >= lend) continue;
            break;
          }
          if (jtot == nmaxit) break;
          jtot++;
          float gg = (dd[l - 1] - pp) / (2.f * ee[l - 1]);
          float rr = slapy2f(gg, 1.f);
          gg = dd[mq] - pp + ee[l - 1] / (gg + copysignf(rr, gg));
          float ss_ = 1.f, cc_ = 1.f;
          pp = 0.f;
          for (int i = mq; i <= l - 1; i++) {
            float ff = ss_ * ee[i];
            float bb = cc_ * ee[i];
            slartgf(gg, ff, &cc_, &ss_, &rr);
            if (i != mq) { if (lane == 0) ee[i - 1] = rr; }
            gg = dd[i] - pp;
            rr = (dd[i + 1] - gg) * ss_ + 2.f * cc_ * bb;
            pp = ss_ * rr;
            if (lane == 0) dd[i] = gg + pp;
            gg = cc_ * rr - bb;
            // apply rotation (c, s) to Z cols (i, i+1); same order as slasr 'F'
            if (lane < 16) {
              float z1 = Zm[lane][i + 1], z0 = Zm[lane][i];
              Zm[lane][i + 1] = cc_ * z1 - ss_ * z0;
              Zm[lane][i] = ss_ * z1 + cc_ * z0;
            }
          }
          if (lane == 0) { dd[l] = dd[l] - pp; ee[l - 1] = gg; }
        }
      }
    }

    // ---- outputs ----
    int k = 0;
    float mx = dd[0];
    for (int j = 1; j < 16; j++) { if (dd[j] > mx) { mx = dd[j]; k = j; } }
    float ratio = mx / trace;
    float x = ratio - bias[o];
    float act = 1.f / (1.f + expf(-x));
    if (lane < 16) out[512 + bo * 16 + lane] = Zm[lane][k];
    if (lane == 0) out[bo] = act;
  }
}

extern "C" void kernel_launch(void* const* d_in, const int* in_sizes, int n_in,
                              void* d_out, int out_size, void* d_ws, size_t ws_size,
                              hipStream_t stream) {
  const float* in = (const float*)d_in[0];
  const float* w = (const float*)d_in[1];
  const float* bias = (const float*)d_in[2];
  float* out = (float*)d_out;
  float* Tmom = (float*)d_ws;  // 512 * 256 floats = 512 KB scratch

  moments_kernel<<<B_ * L_, 256, 0, stream>>>(in, Tmom);
  gram_eig_kernel<<<B_ * O_, 256, 0, stream>>>(Tmom, w, bias, out);
}

// Round 2
// 166.705 us; speedup vs baseline: 1.2935x; 1.2935x over previous
//
#include <hip/hip_runtime.h>

#define B_ 16
#define L_ 32
#define O_ 32
#define M_ 256
#define CH_ 544   // L*(P+1)

// ---------- LAPACK helper transcriptions (f32) ----------

__device__ __forceinline__ float wave_sum64(float v) {
#pragma unroll
  for (int off = 32; off > 0; off >>= 1) v += __shfl_xor(v, off, 64);
  return v;
}

__device__ __forceinline__ float slapy2f(float x, float y) {
  float xa = fabsf(x), ya = fabsf(y);
  float w = fmaxf(xa, ya), z = fminf(xa, ya);
  if (z == 0.f) return w;
  float q = z / w;
  return w * sqrtf(1.f + q * q);
}

// LAPACK >= 3.10 slartg convention (c >= 0, r = sign(f)*hypot); fast rcp form.
__device__ __forceinline__ void slartgf(float f, float g, float* c, float* s, float* r) {
  if (g == 0.f) { *c = 1.f; *s = 0.f; *r = f; }
  else if (f == 0.f) { *c = 0.f; *s = copysignf(1.f, g); *r = fabsf(g); }
  else {
    float d = __builtin_amdgcn_sqrtf(f * f + g * g);
    float inv = __builtin_amdgcn_rcpf(d);
    *c = fabsf(f) * inv;
    *r = copysignf(d, f);
    *s = g * copysignf(inv, f);
  }
}

__device__ __forceinline__ void slaev2f(float a, float b, float c,
                                        float* rt1, float* rt2, float* cs1, float* sn1) {
  float sm = a + c, df = a - c;
  float adf = fabsf(df);
  float tb = b + b;
  float ab = fabsf(tb);
  float acmx, acmn;
  if (fabsf(a) > fabsf(c)) { acmx = a; acmn = c; } else { acmx = c; acmn = a; }
  float rt;
  if (adf > ab) { float q = ab / adf; rt = adf * sqrtf(1.f + q * q); }
  else if (adf < ab) { float q = adf / ab; rt = ab * sqrtf(1.f + q * q); }
  else rt = ab * sqrtf(2.f);
  int sgn1;
  if (sm < 0.f) { *rt1 = 0.5f * (sm - rt); sgn1 = -1; *rt2 = (acmx / *rt1) * acmn - (b / *rt1) * b; }
  else if (sm > 0.f) { *rt1 = 0.5f * (sm + rt); sgn1 = 1; *rt2 = (acmx / *rt1) * acmn - (b / *rt1) * b; }
  else { *rt1 = 0.5f * rt; *rt2 = -0.5f * rt; sgn1 = 1; }
  float cs; int sgn2;
  if (df >= 0.f) { cs = df + rt; sgn2 = 1; } else { cs = df - rt; sgn2 = -1; }
  float acs = fabsf(cs), c1, s1;
  if (acs > ab) { float ct = -tb / cs; s1 = 1.f / sqrtf(1.f + ct * ct); c1 = ct * s1; }
  else if (ab == 0.f) { c1 = 1.f; s1 = 0.f; }
  else { float tn = -cs / tb; c1 = 1.f / sqrtf(1.f + tn * tn); s1 = tn * c1; }
  if (sgn1 == sgn2) { float tn = c1; c1 = -s1; s1 = tn; }
  *cs1 = c1; *sn1 = s1;
}

// ---------- Kernel 1: weighted pose second moments ----------
// T[b,l][r][c] = sum_m (a*p_r)*(a*p_c)
__global__ __launch_bounds__(256) void moments_kernel(const float* __restrict__ in,
                                                      float* __restrict__ Tmom) {
  int bl = blockIdx.x;
  int b = bl >> 5, l = bl & 31;
  __shared__ __align__(16) float ut[16][68];   // ut[channel][m-row], stride 68 (b128-aligned, 2-way banks)
  int t = threadIdx.x;
  int mm = t >> 2, qq = t & 3;                 // staging mapping: row mm, quarter qq
  int r = t >> 4, c = t & 15;                  // MAC mapping
  const float* base = in + (size_t)b * (M_ * CH_);
  const float* prow = base + l * 16 + qq * 4;
  float4 f4 = *(const float4*)(prow + (size_t)mm * CH_);
  float av = base[(size_t)mm * CH_ + 512 + l];
  float acc = 0.f;
  for (int ch = 0; ch < 4; ch++) {
    ut[qq * 4 + 0][mm] = av * f4.x;
    ut[qq * 4 + 1][mm] = av * f4.y;
    ut[qq * 4 + 2][mm] = av * f4.z;
    ut[qq * 4 + 3][mm] = av * f4.w;
    __syncthreads();
    if (ch < 3) {  // prefetch next chunk during MAC
      int m = (ch + 1) * 64 + mm;
      f4 = *(const float4*)(prow + (size_t)m * CH_);
      av = base[(size_t)m * CH_ + 512 + l];
    }
#pragma unroll
    for (int m4 = 0; m4 < 64; m4 += 4) {
      float4 a4 = *(const float4*)&ut[r][m4];
      float4 b4 = *(const float4*)&ut[c][m4];
      acc += a4.x * b4.x + a4.y * b4.y + a4.z * b4.z + a4.w * b4.w;
    }
    __syncthreads();
  }
  Tmom[bl * 256 + t] = acc;
}

// ---------- Kernel 2: gram via T, register-resident LAPACK-replica eigh ----------
__global__ __launch_bounds__(64) void gram_eig_kernel(const float* __restrict__ Tmom,
                                                      const float* __restrict__ Wt,
                                                      const float* __restrict__ bias,
                                                      float* __restrict__ out) {
  int bo = blockIdx.x;
  int b = bo >> 5, o = bo & 31;
  int lane = threadIdx.x;

  __shared__ __align__(16) float4 Wall4[128];   // W[l][16] as 4 float4 per l
  __shared__ __align__(16) float4 Tsh4[4 * 18]; // padded: phys = (m>>4)*18 + (m&15)
  __shared__ float A[16][17];
  __shared__ __align__(16) float Zt[16][16];    // Zt[col][row]
  __shared__ float wvec[16];

  // ---- stage W for all l (o fixed per block) ----
  const float4* Wt4 = (const float4*)Wt;
#pragma unroll
  for (int k = 0; k < 2; k++) {
    int idx = lane + 64 * k;           // 0..127
    int l = idx >> 2, part = idx & 3;
    Wall4[idx] = Wt4[(l * 32 + o) * 4 + part];
  }
  __syncthreads();

  // ---- gram: G[p][q] = sum_l sum_{j,j'} T[(i,j),(i2,j')] W[j][k_] W[j'][k2] ----
  int p = lane >> 2;                   // row of G owned (4 cols per lane)
  int i_ = p >> 2, k_ = p & 3;
  int i2 = lane & 3;                   // q = i2*4 + k2, k2 = 0..3
  float gx = 0.f, gy = 0.f, gz = 0.f, gw = 0.f;
  const float4* T4 = (const float4*)(Tmom + (size_t)(b * 32) * 256);
  const float* WallF = (const float*)Wall4;
  float4 tcur = T4[lane];
  float4 tnxt = T4[64 + lane];
  for (int l = 0; l < 32; l++) {
    __syncthreads();
    Tsh4[(lane >> 4) * 18 + (lane & 15)] = tcur;
    __syncthreads();
    tcur = tnxt;
    if (l + 2 < 32) tnxt = T4[(l + 2) * 64 + lane];
    float4 wq0 = Wall4[l * 4 + 0], wq1 = Wall4[l * 4 + 1];
    float4 wq2 = Wall4[l * 4 + 2], wq3 = Wall4[l * 4 + 3];
#pragma unroll
    for (int jj = 0; jj < 4; jj++) {
      float4 trow = Tsh4[i_ * 18 + jj * 4 + i2];
      float ux = trow.x * wq0.x + trow.y * wq1.x + trow.z * wq2.x + trow.w * wq3.x;
      float uy = trow.x * wq0.y + trow.y * wq1.y + trow.z * wq2.y + trow.w * wq3.y;
      float uz = trow.x * wq0.z + trow.y * wq1.z + trow.z * wq2.z + trow.w * wq3.z;
      float uw = trow.x * wq0.w + trow.y * wq1.w + trow.z * wq2.w + trow.w * wq3.w;
      float wk = WallF[l * 16 + jj * 4 + k_];
      gx += wk * ux; gy += wk * uy; gz += wk * uz; gw += wk * uw;
    }
  }
  {
    int q0 = i2 * 4;
    A[p][q0 + 0] = gx; A[p][q0 + 1] = gy; A[p][q0 + 2] = gz; A[p][q0 + 3] = gw;
  }
  __syncthreads();
  float trace = wave_sum64((lane < 16) ? A[lane][lane] : 0.f);

  // ---- ssytd2 (lower); d,e,tau in lane registers ----
  float dreg = 0.f, ereg = 0.f, taureg = 0.f;
  for (int i = 0; i < 15; i++) {
    float alpha = A[i + 1][i];
    float xv = (lane >= i + 2 && lane < 16) ? A[lane][i] : 0.f;
    float xn2 = wave_sum64(xv * xv);
    float taui;
    if (xn2 == 0.f) {
      taui = 0.f;
      if (lane == i) ereg = alpha;
    } else {
      float xnorm = sqrtf(xn2);
      float beta = -copysignf(slapy2f(alpha, xnorm), alpha);
      taui = (beta - alpha) / beta;
      float rs = 1.f / (alpha - beta);
      if (lane >= i + 2 && lane < 16) A[lane][i] = xv * rs;
      if (lane == i) ereg = beta;
      // w = tau * Asym * v, v[i+1]=1, v[c]=A[c][i] (c>=i+2)
      float wr = 0.f;
      if (lane >= i + 1 && lane < 16) {
        for (int c = i + 1; c < 16; c++) {
          float av = (lane >= c) ? A[lane][c] : A[c][lane];
          float vc = (c == i + 1) ? 1.f : A[c][i];
          wr += av * vc;
        }
        wr *= taui;
      }
      float vr = (lane == i + 1) ? 1.f : ((lane >= i + 2 && lane < 16) ? A[lane][i] : 0.f);
      float dot = wave_sum64(wr * vr);
      float alph2 = -0.5f * taui * dot;
      wr += alph2 * vr;
      if (lane < 16) wvec[lane] = wr;
      if (lane >= i + 1 && lane < 16) {
        float vl = vr;
        for (int c = i + 1; c <= lane; c++) {
          float vc = (c == i + 1) ? 1.f : A[c][i];
          A[lane][c] -= vl * wvec[c] + wr * vc;
        }
      }
    }
    if (lane == i) { dreg = A[i][i]; taureg = taui; }
  }
  if (lane == 15) dreg = A[15][15];

  // ---- form Q = H(1)..H(14); lane = column, rows in registers ----
  float z[16];
#pragma unroll
  for (int r = 0; r < 16; r++) z[r] = (lane == r) ? 1.f : 0.f;
  for (int i = 13; i >= 0; i--) {
    float taui = __shfl(taureg, i, 64);
    if (taui != 0.f) {
      float s = 0.f;
#pragma unroll
      for (int r = 0; r < 16; r++) {
        float vr = (r == i + 1) ? 1.f : ((r >= i + 2) ? A[r][i] : 0.f);
        s += vr * z[r];
      }
      s *= taui;
#pragma unroll
      for (int r = 0; r < 16; r++) {
        float vr = (r == i + 1) ? 1.f : ((r >= i + 2) ? A[r][i] : 0.f);
        z[r] -= vr * s;
      }
    }
  }
  if (lane < 16) {
    float4* zt4 = (float4*)&Zt[lane][0];
    zt4[0] = make_float4(z[0], z[1], z[2], z[3]);
    zt4[1] = make_float4(z[4], z[5], z[6], z[7]);
    zt4[2] = make_float4(z[8], z[9], z[10], z[11]);
    zt4[3] = make_float4(z[12], z[13], z[14], z[15]);
  }
  __syncthreads();

  // ---- ssteqr; d,e in lane registers, ballot-based deflation scans ----
  const float eps = 5.9604645e-08f;
  const float eps2 = eps * eps;
  const float safmin = 1.17549435e-38f;
  int l1 = 0, jtot = 0;
  const int nmaxit = 480;

  while (l1 < 16) {
    if (l1 > 0) { if (lane == l1 - 1) ereg = 0.f; }
    // split scan: m = first j >= l1 with e[j] negligible, else 15
    float dp1 = __shfl(dreg, (lane + 1) & 63, 64);
    bool co = (lane < 15) &&
              ((ereg == 0.f) ||
               (fabsf(ereg) <= __builtin_amdgcn_sqrtf(fabsf(dreg)) *
                                   __builtin_amdgcn_sqrtf(fabsf(dp1)) * eps));
    unsigned long long bm = __ballot(co) & ~((1ull << l1) - 1ull);
    int m = bm ? (__ffsll((unsigned long long)bm) - 1) : 15;
    if (m < 15) { if (lane == m) ereg = 0.f; }
    int l = l1, lend = m;
    l1 = m + 1;
    if (lend == l) continue;
    {
      float dl = __shfl(dreg, l, 64), dle = __shfl(dreg, lend, 64);
      if (fabsf(dle) < fabsf(dl)) { int tq = l; l = lend; lend = tq; }
    }

    if (lend > l) {
      // ---- QL ----
      for (;;) {
        float dp = __shfl(dreg, (lane + 1) & 63, 64);
        bool cj = (lane < 15) && ((ereg * ereg) <= eps2 * fabsf(dreg) * fabsf(dp) + safmin);
        int mq;
        if (l != lend) {
          unsigned long long bb2 = __ballot(cj) & ((1ull << lend) - 1ull) & ~((1ull << l) - 1ull);
          mq = bb2 ? (__ffsll(bb2) - 1) : lend;
        } else mq = lend;
        if (mq < lend) { if (lane == mq) ereg = 0.f; }
        float pp = __shfl(dreg, l, 64);
        if (mq == l) { l++; if (l <= lend) continue; break; }
        if (mq == l + 1) {
          float d_l = __shfl(dreg, l, 64), e_l = __shfl(ereg, l, 64), d_l1 = __shfl(dreg, l + 1, 64);
          float rt1, rt2, cc, ss;
          slaev2f(d_l, e_l, d_l1, &rt1, &rt2, &cc, &ss);
          if (lane < 16) {
            float z1 = Zt[l + 1][lane], z0 = Zt[l][lane];
            Zt[l + 1][lane] = cc * z1 - ss * z0;
            Zt[l][lane] = ss * z1 + cc * z0;
          }
          if (lane == l) { dreg = rt1; ereg = 0.f; }
          if (lane == l + 1) dreg = rt2;
          l += 2; if (l <= lend) continue; break;
        }
        if (jtot == nmaxit) break;
        jtot++;
        float d_l1v = __shfl(dreg, l + 1, 64), e_lv = __shfl(ereg, l, 64), d_mq = __shfl(dreg, mq, 64);
        float gg = (d_l1v - pp) / (2.f * e_lv);
        float rr = slapy2f(gg, 1.f);
        gg = d_mq - pp + e_lv / (gg + copysignf(rr, gg));
        float ss_ = 1.f, cc_ = 1.f;
        pp = 0.f;
        float zc = (lane < 16) ? Zt[mq][lane] : 0.f;   // carried column
        for (int i = mq - 1; i >= l; i--) {
          float e_i = __shfl(ereg, i, 64);     // pre-sweep value
          float d_i = __shfl(dreg, i, 64);     // pre-sweep value
          float d_i1 = __shfl(dreg, i + 1, 64);// pre-sweep value
          float ff = ss_ * e_i, bb = cc_ * e_i;
          slartgf(gg, ff, &cc_, &ss_, &rr);
          if (i != mq - 1) { if (lane == i + 1) ereg = rr; }
          gg = d_i1 - pp;
          rr = (d_i - gg) * ss_ + 2.f * cc_ * bb;
          pp = ss_ * rr;
          if (lane == i + 1) dreg = gg + pp;
          gg = cc_ * rr - bb;
          float z0 = (lane < 16) ? Zt[i][lane] : 0.f;
          if (lane < 16) Zt[i + 1][lane] = cc_ * zc + ss_ * z0;
          zc = -ss_ * zc + cc_ * z0;
        }
        if (lane < 16) Zt[l][lane] = zc;
        if (lane == l) { dreg = dreg - pp; ereg = gg; }
      }
    } else {
      // ---- QR ----
      for (;;) {
        float dp = __shfl(dreg, (lane + 1) & 63, 64);
        bool cj = (lane < 15) && ((ereg * ereg) <= eps2 * fabsf(dp) * fabsf(dreg) + safmin);
        int mq;
        if (l != lend) {
          unsigned long long bb2 = __ballot(cj) & ((1ull << l) - 1ull) & ~((1ull << lend) - 1ull);
          mq = bb2 ? (63 - __clzll(bb2) + 1) : lend;
        } else mq = lend;
        if (mq > lend) { if (lane == mq - 1) ereg = 0.f; }
        float pp = __shfl(dreg, l, 64);
        if (mq == l) { l--; if (l >= lend) continue; break; }
        if (mq == l - 1) {
          float d_lm1 = __shfl(dreg, l - 1, 64), e_lm1 = __shfl(ereg, l - 1, 64), d_l = __shfl(dreg, l, 64);
          float rt1, rt2, cc, ss;
          slaev2f(d_lm1, e_lm1, d_l, &rt1, &rt2, &cc, &ss);
          if (lane < 16) {
            float z1 = Zt[l][lane], z0 = Zt[l - 1][lane];
            Zt[l][lane] = cc * z1 - ss * z0;
            Zt[l - 1][lane] = ss * z1 + cc * z0;
          }
          if (lane == l - 1) { dreg = rt1; ereg = 0.f; }
          if (lane == l) dreg = rt2;
          l -= 2; if (l >= lend) continue; break;
        }
        if (jtot == nmaxit) break;
        jtot++;
        float d_lm1 = __shfl(dreg, l - 1, 64), e_lm1 = __shfl(ereg, l - 1, 64), d_mq = __shfl(dreg, mq, 64);
        float gg = (d_lm1 - pp) / (2.f * e_lm1);
        float rr = slapy2f(gg, 1.f);
        gg = d_mq - pp + e_lm1 / (gg + copysignf(rr, gg));
        float ss_ = 1.f, cc_ = 1.f;
        pp = 0.f;
        float zc = (lane < 16) ? Zt[mq][lane] : 0.f;   // carried column
        for (int i = mq; i <= l - 1; i++) {
          float e_i = __shfl(ereg, i, 64);      // pre-sweep value
          float d_i = __shfl(dreg, i, 64);      // pre-sweep value
          float d_i1 = __shfl(dreg, i + 1, 64); // pre-sweep value
          float ff = ss_ * e_i, bb = cc_ * e_i;
          slartgf(gg, ff, &cc_, &ss_, &rr);
          if (i != mq) { if (lane == i - 1) ereg = rr; }
          gg = d_i - pp;
          rr = (d_i1 - gg) * ss_ + 2.f * cc_ * bb;
          pp = ss_ * rr;
          if (lane == i) dreg = gg + pp;
          gg = cc_ * rr - bb;
          float z1 = (lane < 16) ? Zt[i + 1][lane] : 0.f;
          if (lane < 16) Zt[i][lane] = ss_ * z1 + cc_ * zc;
          zc = cc_ * z1 - ss_ * zc;
        }
        if (lane < 16) Zt[l][lane] = zc;
        if (lane == l) dreg = dreg - pp;
        if (lane == l - 1) ereg = gg;
      }
    }
  }

  // ---- outputs ----
  float mx = __shfl(dreg, 0, 64);
  int k = 0;
  for (int j = 1; j < 16; j++) {
    float dj = __shfl(dreg, j, 64);
    if (dj > mx) { mx = dj; k = j; }
  }
  float ratio = mx / trace;
  float act = 1.f / (1.f + expf(-(ratio - bias[o])));
  if (lane < 16) out[512 + bo * 16 + lane] = Zt[k][lane];
  if (lane == 0) out[bo] = act;
}

extern "C" void kernel_launch(void* const* d_in, const int* in_sizes, int n_in,
                              void* d_out, int out_size, void* d_ws, size_t ws_size,
                              hipStream_t stream) {
  const float* in = (const float*)d_in[0];
  const float* w = (const float*)d_in[1];
  const float* bias = (const float*)d_in[2];
  float* out = (float*)d_out;
  float* Tmom = (float*)d_ws;  // 512 * 256 floats = 512 KB scratch

  moments_kernel<<<B_ * L_, 256, 0, stream>>>(in, Tmom);
  gram_eig_kernel<<<B_ * O_, 64, 0, stream>>>(Tmom, w, bias, out);
}

// Round 3
// 152.271 us; speedup vs baseline: 1.4161x; 1.0948x over previous
//
#include <hip/hip_runtime.h>

#define B_ 16
#define L_ 32
#define O_ 32
#define M_ 256
#define CH_ 544   // L*(P+1)

// ---------- cross-lane helpers ----------

// uniform-index broadcast read: v_readlane (SALU-latency, ~free vs ds_bpermute)
__device__ __forceinline__ float rl(float v, int lane) {
  return __int_as_float(__builtin_amdgcn_readlane(__float_as_int(v), lane));
}

// sum over lanes 0..15 via readlane chain (input must be 0 in lanes >= 16)
__device__ __forceinline__ float sum16_rl(float v) {
  float s = rl(v, 0);
#pragma unroll
  for (int j = 1; j < 16; j++) s += rl(v, j);
  return s;
}

// ---------- LAPACK helper transcriptions (f32) ----------

__device__ __forceinline__ float slapy2f(float x, float y) {
  float xa = fabsf(x), ya = fabsf(y);
  float w = fmaxf(xa, ya), z = fminf(xa, ya);
  if (z == 0.f) return w;
  float q = z / w;
  return w * sqrtf(1.f + q * q);
}

// LAPACK >= 3.10 slartg convention (c >= 0, r = sign(f)*hypot); fast rcp form.
__device__ __forceinline__ void slartgf(float f, float g, float* c, float* s, float* r) {
  if (g == 0.f) { *c = 1.f; *s = 0.f; *r = f; }
  else if (f == 0.f) { *c = 0.f; *s = copysignf(1.f, g); *r = fabsf(g); }
  else {
    float d = __builtin_amdgcn_sqrtf(f * f + g * g);
    float inv = __builtin_amdgcn_rcpf(d);
    *c = fabsf(f) * inv;
    *r = copysignf(d, f);
    *s = g * copysignf(inv, f);
  }
}

__device__ __forceinline__ void slaev2f(float a, float b, float c,
                                        float* rt1, float* rt2, float* cs1, float* sn1) {
  float sm = a + c, df = a - c;
  float adf = fabsf(df);
  float tb = b + b;
  float ab = fabsf(tb);
  float acmx, acmn;
  if (fabsf(a) > fabsf(c)) { acmx = a; acmn = c; } else { acmx = c; acmn = a; }
  float rt;
  if (adf > ab) { float q = ab / adf; rt = adf * sqrtf(1.f + q * q); }
  else if (adf < ab) { float q = adf / ab; rt = ab * sqrtf(1.f + q * q); }
  else rt = ab * sqrtf(2.f);
  int sgn1;
  if (sm < 0.f) { *rt1 = 0.5f * (sm - rt); sgn1 = -1; *rt2 = (acmx / *rt1) * acmn - (b / *rt1) * b; }
  else if (sm > 0.f) { *rt1 = 0.5f * (sm + rt); sgn1 = 1; *rt2 = (acmx / *rt1) * acmn - (b / *rt1) * b; }
  else { *rt1 = 0.5f * rt; *rt2 = -0.5f * rt; sgn1 = 1; }
  float cs; int sgn2;
  if (df >= 0.f) { cs = df + rt; sgn2 = 1; } else { cs = df - rt; sgn2 = -1; }
  float acs = fabsf(cs), c1, s1;
  if (acs > ab) { float ct = -tb / cs; s1 = 1.f / sqrtf(1.f + ct * ct); c1 = ct * s1; }
  else if (ab == 0.f) { c1 = 1.f; s1 = 0.f; }
  else { float tn = -cs / tb; c1 = 1.f / sqrtf(1.f + tn * tn); s1 = tn * c1; }
  if (sgn1 == sgn2) { float tn = c1; c1 = -s1; s1 = tn; }
  *cs1 = c1; *sn1 = s1;
}

// ---------- Kernel 1: weighted pose second moments (barrier-free) ----------
// Each wave owns one 64-row chunk of (b,l); partial T written per chunk.
__global__ __launch_bounds__(256) void moments_kernel(const float* __restrict__ in,
                                                      float* __restrict__ Tmom) {
  int bl = blockIdx.x;
  int b = bl >> 5, l = bl & 31;
  int t = threadIdx.x;
  int w = t >> 6, lane = t & 63;
  __shared__ __align__(16) float ut[4][16][68];   // per-wave private tile
  const float* base = in + (size_t)b * (M_ * CH_);
  const float* row = base + (size_t)(w * 64 + lane) * CH_ + l * 16;
  float4 p0 = *(const float4*)(row + 0);
  float4 p1 = *(const float4*)(row + 4);
  float4 p2 = *(const float4*)(row + 8);
  float4 p3 = *(const float4*)(row + 12);
  float a = row[512 - l * 16 + l];   // base + m*CH_ + 512 + l
  float (*u)[68] = ut[w];
  u[0][lane] = a * p0.x;  u[1][lane] = a * p0.y;  u[2][lane] = a * p0.z;  u[3][lane] = a * p0.w;
  u[4][lane] = a * p1.x;  u[5][lane] = a * p1.y;  u[6][lane] = a * p1.z;  u[7][lane] = a * p1.w;
  u[8][lane] = a * p2.x;  u[9][lane] = a * p2.y;  u[10][lane] = a * p2.z; u[11][lane] = a * p2.w;
  u[12][lane] = a * p3.x; u[13][lane] = a * p3.y; u[14][lane] = a * p3.z; u[15][lane] = a * p3.w;
  asm volatile("" ::: "memory");   // per-wave DS pipe ordering handles the rest
  int c = lane & 15, r0 = lane >> 4;
  float acc0 = 0.f, acc1 = 0.f, acc2 = 0.f, acc3 = 0.f;
#pragma unroll
  for (int m4 = 0; m4 < 64; m4 += 4) {
    float4 cv = *(const float4*)&u[c][m4];
    float4 a0 = *(const float4*)&u[r0][m4];
    float4 a1 = *(const float4*)&u[r0 + 4][m4];
    float4 a2 = *(const float4*)&u[r0 + 8][m4];
    float4 a3 = *(const float4*)&u[r0 + 12][m4];
    acc0 += a0.x * cv.x + a0.y * cv.y + a0.z * cv.z + a0.w * cv.w;
    acc1 += a1.x * cv.x + a1.y * cv.y + a1.z * cv.z + a1.w * cv.w;
    acc2 += a2.x * cv.x + a2.y * cv.y + a2.z * cv.z + a2.w * cv.w;
    acc3 += a3.x * cv.x + a3.y * cv.y + a3.z * cv.z + a3.w * cv.w;
  }
  float* dst = Tmom + ((size_t)bl * 4 + w) * 256;
  dst[r0 * 16 + c] = acc0;
  dst[(r0 + 4) * 16 + c] = acc1;
  dst[(r0 + 8) * 16 + c] = acc2;
  dst[(r0 + 12) * 16 + c] = acc3;
}

// ---------- Kernel 2: gram via T, register-resident LAPACK-replica eigh ----------
__global__ __launch_bounds__(64) void gram_eig_kernel(const float* __restrict__ Tmom,
                                                      const float* __restrict__ Wt,
                                                      const float* __restrict__ bias,
                                                      float* __restrict__ out) {
  int bo = blockIdx.x;
  int b = bo >> 5, o = bo & 31;
  int lane = threadIdx.x;

  __shared__ __align__(16) float4 Wall4[128];   // W[l][16] as 4 float4 per l
  __shared__ __align__(16) float4 Tsh4[4 * 18]; // padded
  __shared__ float A[16][17];
  __shared__ __align__(16) float Zt[16][16];    // Zt[col][row]
  __shared__ float wvec[16];

  // ---- stage W for all l ----
  const float4* Wt4 = (const float4*)Wt;
#pragma unroll
  for (int k = 0; k < 2; k++) {
    int idx = lane + 64 * k;
    int l = idx >> 2, part = idx & 3;
    Wall4[idx] = Wt4[(l * 32 + o) * 4 + part];
  }
  __syncthreads();

  // ---- gram ----
  int p = lane >> 2;
  int i_ = p >> 2, k_ = p & 3;
  int i2 = lane & 3;
  float gx = 0.f, gy = 0.f, gz = 0.f, gw = 0.f;
  const float4* T4b = (const float4*)Tmom + (size_t)(b * 32) * 4 * 64;
  const float* WallF = (const float*)Wall4;
  float4 tc0 = T4b[0 * 64 + lane], tc1 = T4b[1 * 64 + lane];
  float4 tc2 = T4b[2 * 64 + lane], tc3 = T4b[3 * 64 + lane];
  float4 tn0 = T4b[4 * 64 + lane], tn1 = T4b[5 * 64 + lane];
  float4 tn2 = T4b[6 * 64 + lane], tn3 = T4b[7 * 64 + lane];
  for (int l = 0; l < 32; l++) {
    float4 tsum;
    tsum.x = (tc0.x + tc1.x) + (tc2.x + tc3.x);
    tsum.y = (tc0.y + tc1.y) + (tc2.y + tc3.y);
    tsum.z = (tc0.z + tc1.z) + (tc2.z + tc3.z);
    tsum.w = (tc0.w + tc1.w) + (tc2.w + tc3.w);
    __syncthreads();
    Tsh4[(lane >> 4) * 18 + (lane & 15)] = tsum;
    __syncthreads();
    tc0 = tn0; tc1 = tn1; tc2 = tn2; tc3 = tn3;
    if (l + 2 < 32) {
      const float4* nb = T4b + (size_t)(l + 2) * 4 * 64;
      tn0 = nb[0 * 64 + lane]; tn1 = nb[1 * 64 + lane];
      tn2 = nb[2 * 64 + lane]; tn3 = nb[3 * 64 + lane];
    }
    float4 wq0 = Wall4[l * 4 + 0], wq1 = Wall4[l * 4 + 1];
    float4 wq2 = Wall4[l * 4 + 2], wq3 = Wall4[l * 4 + 3];
#pragma unroll
    for (int jj = 0; jj < 4; jj++) {
      float4 trow = Tsh4[i_ * 18 + jj * 4 + i2];
      float ux = trow.x * wq0.x + trow.y * wq1.x + trow.z * wq2.x + trow.w * wq3.x;
      float uy = trow.x * wq0.y + trow.y * wq1.y + trow.z * wq2.y + trow.w * wq3.y;
      float uz = trow.x * wq0.z + trow.y * wq1.z + trow.z * wq2.z + trow.w * wq3.z;
      float uw = trow.x * wq0.w + trow.y * wq1.w + trow.z * wq2.w + trow.w * wq3.w;
      float wk = WallF[l * 16 + jj * 4 + k_];
      gx += wk * ux; gy += wk * uy; gz += wk * uz; gw += wk * uw;
    }
  }
  {
    int q0 = i2 * 4;
    A[p][q0 + 0] = gx; A[p][q0 + 1] = gy; A[p][q0 + 2] = gz; A[p][q0 + 3] = gw;
  }
  __syncthreads();
  float trace = sum16_rl((lane < 16) ? A[lane][lane] : 0.f);

  // ---- ssytd2 (lower); d,e,tau in lane registers ----
  float dreg = 0.f, ereg = 0.f, taureg = 0.f;
  for (int i = 0; i < 15; i++) {
    float alpha = A[i + 1][i];
    float xv = (lane >= i + 2 && lane < 16) ? A[lane][i] : 0.f;
    float xn2 = sum16_rl(xv * xv);
    float taui;
    if (xn2 == 0.f) {
      taui = 0.f;
      if (lane == i) ereg = alpha;
    } else {
      float xnorm = sqrtf(xn2);
      float beta = -copysignf(slapy2f(alpha, xnorm), alpha);
      taui = (beta - alpha) / beta;
      float rs = 1.f / (alpha - beta);
      if (lane >= i + 2 && lane < 16) A[lane][i] = xv * rs;
      if (lane == i) ereg = beta;
      float wr = 0.f;
      if (lane >= i + 1 && lane < 16) {
        for (int cc = i + 1; cc < 16; cc++) {
          float av = (lane >= cc) ? A[lane][cc] : A[cc][lane];
          float vc = (cc == i + 1) ? 1.f : A[cc][i];
          wr += av * vc;
        }
        wr *= taui;
      }
      float vr = (lane == i + 1) ? 1.f : ((lane >= i + 2 && lane < 16) ? A[lane][i] : 0.f);
      float dot = sum16_rl(wr * vr);
      float alph2 = -0.5f * taui * dot;
      wr += alph2 * vr;
      if (lane < 16) wvec[lane] = wr;
      if (lane >= i + 1 && lane < 16) {
        float vl = vr;
        for (int cc = i + 1; cc <= lane; cc++) {
          float vc = (cc == i + 1) ? 1.f : A[cc][i];
          A[lane][cc] -= vl * wvec[cc] + wr * vc;
        }
      }
    }
    if (lane == i) { dreg = A[i][i]; taureg = taui; }
  }
  if (lane == 15) dreg = A[15][15];

  // ---- form Q = H(1)..H(14); lane = column, rows in registers ----
  float z[16];
#pragma unroll
  for (int r = 0; r < 16; r++) z[r] = (lane == r) ? 1.f : 0.f;
  for (int i = 13; i >= 0; i--) {
    float taui = rl(taureg, i);
    if (taui != 0.f) {
      float s = 0.f;
#pragma unroll
      for (int r = 0; r < 16; r++) {
        float vr = (r == i + 1) ? 1.f : ((r >= i + 2) ? A[r][i] : 0.f);
        s += vr * z[r];
      }
      s *= taui;
#pragma unroll
      for (int r = 0; r < 16; r++) {
        float vr = (r == i + 1) ? 1.f : ((r >= i + 2) ? A[r][i] : 0.f);
        z[r] -= vr * s;
      }
    }
  }
  if (lane < 16) {
    float4* zt4 = (float4*)&Zt[lane][0];
    zt4[0] = make_float4(z[0], z[1], z[2], z[3]);
    zt4[1] = make_float4(z[4], z[5], z[6], z[7]);
    zt4[2] = make_float4(z[8], z[9], z[10], z[11]);
    zt4[3] = make_float4(z[12], z[13], z[14], z[15]);
  }
  __syncthreads();

  // ---- ssteqr; d,e in lane registers; readlane snapshots; dsh = d[lane+1] ----
  const float eps = 5.9604645e-08f;
  const float eps2 = eps * eps;
  const float safmin = 1.17549435e-38f;
  int l1 = 0, jtot = 0;
  const int nmaxit = 480;
  float dsh = __shfl(dreg, (lane + 1) & 63, 64);   // one-time shuffle

  while (l1 < 16) {
    if (l1 > 0) { if (lane == l1 - 1) ereg = 0.f; }
    bool co = (lane < 15) &&
              ((ereg == 0.f) ||
               (fabsf(ereg) <= __builtin_amdgcn_sqrtf(fabsf(dreg)) *
                                   __builtin_amdgcn_sqrtf(fabsf(dsh)) * eps));
    unsigned long long bm = __ballot(co) & ~((1ull << l1) - 1ull);
    int m = bm ? (__ffsll(bm) - 1) : 15;
    if (m < 15) { if (lane == m) ereg = 0.f; }
    int l = l1, lend = m;
    l1 = m + 1;
    if (lend == l) continue;
    {
      float dl = rl(dreg, l), dle = rl(dreg, lend);
      if (fabsf(dle) < fabsf(dl)) { int tq = l; l = lend; lend = tq; }
    }

    if (lend > l) {
      // ---- QL ----
      for (;;) {
        bool cj = (lane < 15) && ((ereg * ereg) <= eps2 * fabsf(dreg) * fabsf(dsh) + safmin);
        int mq;
        if (l != lend) {
          unsigned long long bb2 = __ballot(cj) & ((1ull << lend) - 1ull) & ~((1ull << l) - 1ull);
          mq = bb2 ? (__ffsll(bb2) - 1) : lend;
        } else mq = lend;
        if (mq < lend) { if (lane == mq) ereg = 0.f; }
        if (mq == l) { l++; if (l <= lend) continue; break; }
        if (mq == l + 1) {
          float d_l = rl(dreg, l), e_l = rl(ereg, l), d_l1 = rl(dreg, l + 1);
          float rt1, rt2, cc, ss;
          slaev2f(d_l, e_l, d_l1, &rt1, &rt2, &cc, &ss);
          if (lane < 16) {
            float z1 = Zt[l + 1][lane], z0 = Zt[l][lane];
            Zt[l + 1][lane] = cc * z1 - ss * z0;
            Zt[l][lane] = ss * z1 + cc * z0;
          }
          if (lane == l) { dreg = rt1; ereg = 0.f; dsh = rt2; }
          if (lane == l + 1) dreg = rt2;
          if (lane == l - 1) dsh = rt1;
          l += 2; if (l <= lend) continue; break;
        }
        if (jtot == nmaxit) break;
        jtot++;
        float d0 = dreg, e0 = ereg;     // pre-sweep snapshots (off-chain reads)
        float pp = rl(d0, l);
        float e_lv = rl(e0, l);
        float gg = (rl(d0, l + 1) - pp) / (2.f * e_lv);
        float rr = slapy2f(gg, 1.f);
        gg = rl(d0, mq) - pp + e_lv / (gg + copysignf(rr, gg));
        float ss_ = 1.f, cc_ = 1.f;
        pp = 0.f;
        float zc = (lane < 16) ? Zt[mq][lane] : 0.f;
        for (int i = mq - 1; i >= l; i--) {
          float z0 = (lane < 16) ? Zt[i][lane] : 0.f;    // issue early
          float e_i = rl(e0, i), d_i = rl(d0, i), d_i1 = rl(d0, i + 1);
          float ff = ss_ * e_i, bb = cc_ * e_i;
          slartgf(gg, ff, &cc_, &ss_, &rr);
          if (i != mq - 1) { if (lane == i + 1) ereg = rr; }
          gg = d_i1 - pp;
          rr = (d_i - gg) * ss_ + 2.f * cc_ * bb;
          pp = ss_ * rr;
          float dnew = gg + pp;
          if (lane == i + 1) dreg = dnew;
          if (lane == i) dsh = dnew;
          gg = cc_ * rr - bb;
          if (lane < 16) Zt[i + 1][lane] = cc_ * zc + ss_ * z0;
          zc = -ss_ * zc + cc_ * z0;
        }
        if (lane < 16) Zt[l][lane] = zc;
        float dlv = rl(d0, l) - pp;
        if (lane == l) { dreg = dlv; ereg = gg; }
        if (lane == l - 1) dsh = dlv;
      }
    } else {
      // ---- QR ----
      for (;;) {
        bool cj = (lane < 15) && ((ereg * ereg) <= eps2 * fabsf(dreg) * fabsf(dsh) + safmin);
        int mq;
        if (l != lend) {
          unsigned long long bb2 = __ballot(cj) & ((1ull << l) - 1ull) & ~((1ull << lend) - 1ull);
          mq = bb2 ? (63 - __clzll(bb2) + 1) : lend;
        } else mq = lend;
        if (mq > lend) { if (lane == mq - 1) ereg = 0.f; }
        if (mq == l) { l--; if (l >= lend) continue; break; }
        if (mq == l - 1) {
          float d_lm1 = rl(dreg, l - 1), e_lm1 = rl(ereg, l - 1), d_l = rl(dreg, l);
          float rt1, rt2, cc, ss;
          slaev2f(d_lm1, e_lm1, d_l, &rt1, &rt2, &cc, &ss);
          if (lane < 16) {
            float z1 = Zt[l][lane], z0 = Zt[l - 1][lane];
            Zt[l][lane] = cc * z1 - ss * z0;
            Zt[l - 1][lane] = ss * z1 + cc * z0;
          }
          if (lane == l - 1) { dreg = rt1; ereg = 0.f; dsh = rt2; }
          if (lane == l) dreg = rt2;
          if (lane == l - 2) dsh = rt1;
          l -= 2; if (l >= lend) continue; break;
        }
        if (jtot == nmaxit) break;
        jtot++;
        float d0 = dreg, e0 = ereg;     // pre-sweep snapshots
        float pp = rl(d0, l);
        float e_lm1 = rl(e0, l - 1);
        float gg = (rl(d0, l - 1) - pp) / (2.f * e_lm1);
        float rr = slapy2f(gg, 1.f);
        gg = rl(d0, mq) - pp + e_lm1 / (gg + copysignf(rr, gg));
        float ss_ = 1.f, cc_ = 1.f;
        pp = 0.f;
        float zc = (lane < 16) ? Zt[mq][lane] : 0.f;
        for (int i = mq; i <= l - 1; i++) {
          float z1 = (lane < 16) ? Zt[i + 1][lane] : 0.f;  // issue early
          float e_i = rl(e0, i), d_i = rl(d0, i), d_i1 = rl(d0, i + 1);
          float ff = ss_ * e_i, bb = cc_ * e_i;
          slartgf(gg, ff, &cc_, &ss_, &rr);
          if (i != mq) { if (lane == i - 1) ereg = rr; }
          gg = d_i - pp;
          rr = (d_i1 - gg) * ss_ + 2.f * cc_ * bb;
          pp = ss_ * rr;
          float dnew = gg + pp;
          if (lane == i) dreg = dnew;
          if (lane == i - 1) dsh = dnew;
          gg = cc_ * rr - bb;
          if (lane < 16) Zt[i][lane] = ss_ * z1 + cc_ * zc;
          zc = cc_ * z1 - ss_ * zc;
        }
        if (lane < 16) Zt[l][lane] = zc;
        float dlv = rl(d0, l) - pp;
        if (lane == l) dreg = dlv;
        if (lane == l - 1) { ereg = gg; dsh = dlv; }
      }
    }
  }

  // ---- outputs ----
  float mx = rl(dreg, 0);
  int k = 0;
#pragma unroll
  for (int j = 1; j < 16; j++) {
    float dj = rl(dreg, j);
    if (dj > mx) { mx = dj; k = j; }
  }
  float ratio = mx / trace;
  float act = 1.f / (1.f + expf(-(ratio - bias[o])));
  if (lane < 16) out[512 + bo * 16 + lane] = Zt[k][lane];
  if (lane == 0) out[bo] = act;
}

extern "C" void kernel_launch(void* const* d_in, const int* in_sizes, int n_in,
                              void* d_out, int out_size, void* d_ws, size_t ws_size,
                              hipStream_t stream) {
  const float* in = (const float*)d_in[0];
  const float* w = (const float*)d_in[1];
  const float* bias = (const float*)d_in[2];
  float* out = (float*)d_out;
  float* Tmom = (float*)d_ws;  // 512 * 4 * 256 floats = 2 MB scratch

  moments_kernel<<<B_ * L_, 256, 0, stream>>>(in, Tmom);
  gram_eig_kernel<<<B_ * O_, 64, 0, stream>>>(Tmom, w, bias, out);
}

// Round 4
// 132.589 us; speedup vs baseline: 1.6263x; 1.1484x over previous
//
#include <hip/hip_runtime.h>

#define B_ 16
#define L_ 32
#define O_ 32
#define M_ 256
#define CH_ 544   // L*(P+1)

// ---------- cross-lane helpers ----------

__device__ __forceinline__ float rl(float v, int lane) {
  return __int_as_float(__builtin_amdgcn_readlane(__float_as_int(v), lane));
}

__device__ __forceinline__ float sum16_rl(float v) {
  float s = rl(v, 0);
#pragma unroll
  for (int j = 1; j < 16; j++) s += rl(v, j);
  return s;
}

__device__ __forceinline__ float frcp(float x) { return __builtin_amdgcn_rcpf(x); }
__device__ __forceinline__ float frsq(float x) { return __builtin_amdgcn_rsqf(x); }

// ---------- LAPACK helper transcriptions (f32) ----------

__device__ __forceinline__ float slapy2f(float x, float y) {
  float xa = fabsf(x), ya = fabsf(y);
  float w = fmaxf(xa, ya), z = fminf(xa, ya);
  if (z == 0.f) return w;
  float q = z * frcp(w);
  return w * sqrtf(1.f + q * q);
}

// LAPACK >= 3.10 slartg convention; single-rsq form.
__device__ __forceinline__ void slartgf(float f, float g, float* c, float* s, float* r) {
  if (g == 0.f) { *c = 1.f; *s = 0.f; *r = f; }
  else if (f == 0.f) { *c = 0.f; *s = copysignf(1.f, g); *r = fabsf(g); }
  else {
    float t = f * f + g * g;
    float inv = frsq(t);
    float d = t * inv;              // sqrt(t)
    *c = fabsf(f) * inv;
    *r = copysignf(d, f);
    *s = g * copysignf(inv, f);
  }
}

__device__ __forceinline__ void slaev2f(float a, float b, float c,
                                        float* rt1, float* rt2, float* cs1, float* sn1) {
  float sm = a + c, df = a - c;
  float adf = fabsf(df);
  float tb = b + b;
  float ab = fabsf(tb);
  float acmx, acmn;
  if (fabsf(a) > fabsf(c)) { acmx = a; acmn = c; } else { acmx = c; acmn = a; }
  float rt;
  if (adf > ab) { float q = ab / adf; rt = adf * sqrtf(1.f + q * q); }
  else if (adf < ab) { float q = adf / ab; rt = ab * sqrtf(1.f + q * q); }
  else rt = ab * sqrtf(2.f);
  int sgn1;
  if (sm < 0.f) { *rt1 = 0.5f * (sm - rt); sgn1 = -1; *rt2 = (acmx / *rt1) * acmn - (b / *rt1) * b; }
  else if (sm > 0.f) { *rt1 = 0.5f * (sm + rt); sgn1 = 1; *rt2 = (acmx / *rt1) * acmn - (b / *rt1) * b; }
  else { *rt1 = 0.5f * rt; *rt2 = -0.5f * rt; sgn1 = 1; }
  float cs; int sgn2;
  if (df >= 0.f) { cs = df + rt; sgn2 = 1; } else { cs = df - rt; sgn2 = -1; }
  float acs = fabsf(cs), c1, s1;
  if (acs > ab) { float ct = -tb / cs; s1 = 1.f / sqrtf(1.f + ct * ct); c1 = ct * s1; }
  else if (ab == 0.f) { c1 = 1.f; s1 = 0.f; }
  else { float tn = -cs / tb; c1 = 1.f / sqrtf(1.f + tn * tn); s1 = tn * c1; }
  if (sgn1 == sgn2) { float tn = c1; c1 = -s1; s1 = tn; }
  *cs1 = c1; *sn1 = s1;
}

// ---------- Kernel 1: weighted pose second moments (barrier-free) ----------
__global__ __launch_bounds__(256) void moments_kernel(const float* __restrict__ in,
                                                      float* __restrict__ Tmom) {
  int bl = blockIdx.x;
  int b = bl >> 5, l = bl & 31;
  int t = threadIdx.x;
  int w = t >> 6, lane = t & 63;
  __shared__ __align__(16) float ut[4][16][68];
  const float* base = in + (size_t)b * (M_ * CH_);
  const float* row = base + (size_t)(w * 64 + lane) * CH_ + l * 16;
  float4 p0 = *(const float4*)(row + 0);
  float4 p1 = *(const float4*)(row + 4);
  float4 p2 = *(const float4*)(row + 8);
  float4 p3 = *(const float4*)(row + 12);
  float a = row[512 - l * 16 + l];
  float (*u)[68] = ut[w];
  u[0][lane] = a * p0.x;  u[1][lane] = a * p0.y;  u[2][lane] = a * p0.z;  u[3][lane] = a * p0.w;
  u[4][lane] = a * p1.x;  u[5][lane] = a * p1.y;  u[6][lane] = a * p1.z;  u[7][lane] = a * p1.w;
  u[8][lane] = a * p2.x;  u[9][lane] = a * p2.y;  u[10][lane] = a * p2.z; u[11][lane] = a * p2.w;
  u[12][lane] = a * p3.x; u[13][lane] = a * p3.y; u[14][lane] = a * p3.z; u[15][lane] = a * p3.w;
  asm volatile("" ::: "memory");
  int c = lane & 15, r0 = lane >> 4;
  float acc0 = 0.f, acc1 = 0.f, acc2 = 0.f, acc3 = 0.f;
#pragma unroll
  for (int m4 = 0; m4 < 64; m4 += 4) {
    float4 cv = *(const float4*)&u[c][m4];
    float4 a0 = *(const float4*)&u[r0][m4];
    float4 a1 = *(const float4*)&u[r0 + 4][m4];
    float4 a2 = *(const float4*)&u[r0 + 8][m4];
    float4 a3 = *(const float4*)&u[r0 + 12][m4];
    acc0 += a0.x * cv.x + a0.y * cv.y + a0.z * cv.z + a0.w * cv.w;
    acc1 += a1.x * cv.x + a1.y * cv.y + a1.z * cv.z + a1.w * cv.w;
    acc2 += a2.x * cv.x + a2.y * cv.y + a2.z * cv.z + a2.w * cv.w;
    acc3 += a3.x * cv.x + a3.y * cv.y + a3.z * cv.z + a3.w * cv.w;
  }
  float* dst = Tmom + ((size_t)bl * 4 + w) * 256;
  dst[r0 * 16 + c] = acc0;
  dst[(r0 + 4) * 16 + c] = acc1;
  dst[(r0 + 8) * 16 + c] = acc2;
  dst[(r0 + 12) * 16 + c] = acc3;
}

// ---------- Kernel 2: gram + register-resident LAPACK-replica eigh ----------
__global__ __launch_bounds__(64) void gram_eig_kernel(const float* __restrict__ Tmom,
                                                      const float* __restrict__ Wt,
                                                      const float* __restrict__ bias,
                                                      float* __restrict__ out) {
  int bo = blockIdx.x;
  int b = bo >> 5, o = bo & 31;
  int lane = threadIdx.x;

  __shared__ __align__(16) float4 Wall4[128];
  __shared__ __align__(16) float4 Tsh4[4 * 18];
  __shared__ float A[16][17];
  __shared__ __align__(16) float Zt[16][16];

  // ---- stage W (single wave: DS in-order, no barrier) ----
  const float4* Wt4 = (const float4*)Wt;
#pragma unroll
  for (int k = 0; k < 2; k++) {
    int idx = lane + 64 * k;
    int l = idx >> 2, part = idx & 3;
    Wall4[idx] = Wt4[(l * 32 + o) * 4 + part];
  }
  asm volatile("" ::: "memory");

  // ---- gram (barrier-free; 1 wave) ----
  int p = lane >> 2;
  int i_ = p >> 2, k_ = p & 3;
  int i2 = lane & 3;
  float gx = 0.f, gy = 0.f, gz = 0.f, gw = 0.f;
  const float4* T4b = (const float4*)Tmom + (size_t)(b * 32) * 4 * 64;
  const float* WallF = (const float*)Wall4;
  float4 tc0 = T4b[0 * 64 + lane], tc1 = T4b[1 * 64 + lane];
  float4 tc2 = T4b[2 * 64 + lane], tc3 = T4b[3 * 64 + lane];
  float4 tn0 = T4b[4 * 64 + lane], tn1 = T4b[5 * 64 + lane];
  float4 tn2 = T4b[6 * 64 + lane], tn3 = T4b[7 * 64 + lane];
  for (int l = 0; l < 32; l++) {
    float4 tsum;
    tsum.x = (tc0.x + tc1.x) + (tc2.x + tc3.x);
    tsum.y = (tc0.y + tc1.y) + (tc2.y + tc3.y);
    tsum.z = (tc0.z + tc1.z) + (tc2.z + tc3.z);
    tsum.w = (tc0.w + tc1.w) + (tc2.w + tc3.w);
    Tsh4[(lane >> 4) * 18 + (lane & 15)] = tsum;
    asm volatile("" ::: "memory");
    tc0 = tn0; tc1 = tn1; tc2 = tn2; tc3 = tn3;
    if (l + 2 < 32) {
      const float4* nb = T4b + (size_t)(l + 2) * 4 * 64;
      tn0 = nb[0 * 64 + lane]; tn1 = nb[1 * 64 + lane];
      tn2 = nb[2 * 64 + lane]; tn3 = nb[3 * 64 + lane];
    }
    float4 wq0 = Wall4[l * 4 + 0], wq1 = Wall4[l * 4 + 1];
    float4 wq2 = Wall4[l * 4 + 2], wq3 = Wall4[l * 4 + 3];
#pragma unroll
    for (int jj = 0; jj < 4; jj++) {
      float4 trow = Tsh4[i_ * 18 + jj * 4 + i2];
      float ux = trow.x * wq0.x + trow.y * wq1.x + trow.z * wq2.x + trow.w * wq3.x;
      float uy = trow.x * wq0.y + trow.y * wq1.y + trow.z * wq2.y + trow.w * wq3.y;
      float uz = trow.x * wq0.z + trow.y * wq1.z + trow.z * wq2.z + trow.w * wq3.z;
      float uw = trow.x * wq0.w + trow.y * wq1.w + trow.z * wq2.w + trow.w * wq3.w;
      float wk = WallF[l * 16 + jj * 4 + k_];
      gx += wk * ux; gy += wk * uy; gz += wk * uz; gw += wk * uw;
    }
    asm volatile("" ::: "memory");
  }
  {
    int q0 = i2 * 4;
    A[p][q0 + 0] = gx; A[p][q0 + 1] = gy; A[p][q0 + 2] = gz; A[p][q0 + 3] = gw;
  }
  asm volatile("" ::: "memory");

  // ---- load A columns into registers: lane c holds a[r] = A[r][c] ----
  int c16 = lane & 15;
  float a[16];
#pragma unroll
  for (int r = 0; r < 16; r++) a[r] = A[r][c16];

  float trace;
  {
    float diag = 0.f;
#pragma unroll
    for (int r = 0; r < 16; r++) if (c16 == r) diag = a[r];
    trace = sum16_rl((lane < 16) ? diag : 0.f);
  }

  // ---- ssytd2 (lower), fully register-resident, fully unrolled ----
  float dreg = 0.f, ereg = 0.f, taureg = 0.f;
  float hv[14];
#pragma unroll
  for (int i = 0; i < 15; i++) {
    float cn = 0.f;
#pragma unroll
    for (int r = i + 2; r < 16; r++) cn += a[r] * a[r];
    float xn2 = rl(cn, i);                 // ||A[i+2..15][i]||^2 (symmetry: col i = a[i] of lane i)
    float alpha = rl(a[i + 1], i);
    float taui = 0.f;
    float vc = 0.f;
    if (xn2 == 0.f) {
      if (lane == i) ereg = alpha;
    } else {
      float xnorm = sqrtf(xn2);
      float beta = -copysignf(slapy2f(alpha, xnorm), alpha);
      taui = (beta - alpha) / beta;
      float rs = 1.f / (alpha - beta);
      if (lane == i) ereg = beta;
      // per-lane v scalar (v along rows; lane c holds v[c]); A[c][i] = a[i] by symmetry
      vc = (lane == i + 1) ? 1.f : ((lane >= i + 2 && lane < 16) ? a[i] * rs : 0.f);
      float vb[16];
#pragma unroll
      for (int r = i + 1; r < 16; r++) vb[r] = rl(vc, r);
      float acc = 0.f;
#pragma unroll
      for (int r = i + 1; r < 16; r++) acc += a[r] * vb[r];   // (A v)_c in-lane
      float wc = (lane >= i + 1 && lane < 16) ? taui * acc : 0.f;
      float wb[16];
#pragma unroll
      for (int r = i + 1; r < 16; r++) wb[r] = rl(wc, r);
      float dot = 0.f;
#pragma unroll
      for (int r = i + 1; r < 16; r++) dot += vb[r] * wb[r];  // v^T w (uniform)
      float alph2 = -0.5f * taui * dot;
      wc += alph2 * vc;
#pragma unroll
      for (int r = i + 1; r < 16; r++) wb[r] += alph2 * vb[r];
#pragma unroll
      for (int r = i + 1; r < 16; r++) a[r] -= vb[r] * wc + wb[r] * vc;  // rank-2
    }
    if (i < 14) hv[i] = vc;
    if (lane == i) taureg = taui;
  }
#pragma unroll
  for (int r = 0; r < 16; r++) if (c16 == r) dreg = a[r];
  if (lane >= 16) dreg = 0.f;

  // ---- form Q = H(1)..H(14); lane = column, rows in registers ----
  float z[16];
#pragma unroll
  for (int r = 0; r < 16; r++) z[r] = (lane == r) ? 1.f : 0.f;
#pragma unroll
  for (int i = 13; i >= 0; i--) {
    float taui = rl(taureg, i);
    if (taui != 0.f) {
      float vbq[16];
      float s = 0.f;
#pragma unroll
      for (int r = i + 1; r < 16; r++) { vbq[r] = rl(hv[i], r); s += vbq[r] * z[r]; }
      s *= taui;
#pragma unroll
      for (int r = i + 1; r < 16; r++) z[r] -= vbq[r] * s;
    }
  }
  if (lane < 16) {
    float4* zt4 = (float4*)&Zt[lane][0];
    zt4[0] = make_float4(z[0], z[1], z[2], z[3]);
    zt4[1] = make_float4(z[4], z[5], z[6], z[7]);
    zt4[2] = make_float4(z[8], z[9], z[10], z[11]);
    zt4[3] = make_float4(z[12], z[13], z[14], z[15]);
  }
  asm volatile("" ::: "memory");

  // ---- ssteqr; d,e in lane registers; readlane snapshots; dsh = d[lane+1] ----
  const float eps = 5.9604645e-08f;
  const float eps2 = eps * eps;
  const float safmin = 1.17549435e-38f;
  int l1 = 0, jtot = 0;
  const int nmaxit = 480;
  float dsh = __shfl(dreg, (lane + 1) & 63, 64);

  while (l1 < 16) {
    if (l1 > 0) { if (lane == l1 - 1) ereg = 0.f; }
    bool co = (lane < 15) &&
              ((ereg == 0.f) ||
               (fabsf(ereg) <= __builtin_amdgcn_sqrtf(fabsf(dreg)) *
                                   __builtin_amdgcn_sqrtf(fabsf(dsh)) * eps));
    unsigned long long bm = __ballot(co) & ~((1ull << l1) - 1ull);
    int m = bm ? (__ffsll(bm) - 1) : 15;
    if (m < 15) { if (lane == m) ereg = 0.f; }
    int l = l1, lend = m;
    l1 = m + 1;
    if (lend == l) continue;
    {
      float dl = rl(dreg, l), dle = rl(dreg, lend);
      if (fabsf(dle) < fabsf(dl)) { int tq = l; l = lend; lend = tq; }
    }

    if (lend > l) {
      // ---- QL ----
      for (;;) {
        bool cj = (lane < 15) && ((ereg * ereg) <= eps2 * fabsf(dreg) * fabsf(dsh) + safmin);
        int mq;
        if (l != lend) {
          unsigned long long bb2 = __ballot(cj) & ((1ull << lend) - 1ull) & ~((1ull << l) - 1ull);
          mq = bb2 ? (__ffsll(bb2) - 1) : lend;
        } else mq = lend;
        if (mq < lend) { if (lane == mq) ereg = 0.f; }
        if (mq == l) { l++; if (l <= lend) continue; break; }
        if (mq == l + 1) {
          float d_l = rl(dreg, l), e_l = rl(ereg, l), d_l1 = rl(dreg, l + 1);
          float rt1, rt2, cc, ss;
          slaev2f(d_l, e_l, d_l1, &rt1, &rt2, &cc, &ss);
          if (lane < 16) {
            float z1 = Zt[l + 1][lane], z0 = Zt[l][lane];
            Zt[l + 1][lane] = cc * z1 - ss * z0;
            Zt[l][lane] = ss * z1 + cc * z0;
          }
          if (lane == l) { dreg = rt1; ereg = 0.f; dsh = rt2; }
          if (lane == l + 1) dreg = rt2;
          if (lane == l - 1) dsh = rt1;
          l += 2; if (l <= lend) continue; break;
        }
        if (jtot == nmaxit) break;
        jtot++;
        float d0 = dreg, e0 = ereg;
        float pp = rl(d0, l);
        float e_lv = rl(e0, l);
        float gg = (rl(d0, l + 1) - pp) * 0.5f * frcp(e_lv);
        float rr = slapy2f(gg, 1.f);
        gg = rl(d0, mq) - pp + e_lv * frcp(gg + copysignf(rr, gg));
        float ss_ = 1.f, cc_ = 1.f;
        pp = 0.f;
        float zc = (lane < 16) ? Zt[mq][lane] : 0.f;
        float znxt = (lane < 16) ? Zt[mq - 1][lane] : 0.f;  // prefetch
        for (int i = mq - 1; i >= l; i--) {
          float z0 = znxt;
          if (i > l) znxt = (lane < 16) ? Zt[i - 1][lane] : 0.f;  // prefetch next
          float e_i = rl(e0, i), d_i = rl(d0, i), d_i1 = rl(d0, i + 1);
          float ff = ss_ * e_i, bb = cc_ * e_i;
          slartgf(gg, ff, &cc_, &ss_, &rr);
          if (i != mq - 1) { if (lane == i + 1) ereg = rr; }
          gg = d_i1 - pp;
          rr = (d_i - gg) * ss_ + 2.f * cc_ * bb;
          pp = ss_ * rr;
          float dnew = gg + pp;
          if (lane == i + 1) dreg = dnew;
          if (lane == i) dsh = dnew;
          gg = cc_ * rr - bb;
          if (lane < 16) Zt[i + 1][lane] = cc_ * zc + ss_ * z0;
          zc = -ss_ * zc + cc_ * z0;
        }
        if (lane < 16) Zt[l][lane] = zc;
        float dlv = rl(d0, l) - pp;
        if (lane == l) { dreg = dlv; ereg = gg; }
        if (lane == l - 1) dsh = dlv;
      }
    } else {
      // ---- QR ----
      for (;;) {
        bool cj = (lane < 15) && ((ereg * ereg) <= eps2 * fabsf(dreg) * fabsf(dsh) + safmin);
        int mq;
        if (l != lend) {
          unsigned long long bb2 = __ballot(cj) & ((1ull << l) - 1ull) & ~((1ull << lend) - 1ull);
          mq = bb2 ? (63 - __clzll(bb2) + 1) : lend;
        } else mq = lend;
        if (mq > lend) { if (lane == mq - 1) ereg = 0.f; }
        if (mq == l) { l--; if (l >= lend) continue; break; }
        if (mq == l - 1) {
          float d_lm1 = rl(dreg, l - 1), e_lm1 = rl(ereg, l - 1), d_l = rl(dreg, l);
          float rt1, rt2, cc, ss;
          slaev2f(d_lm1, e_lm1, d_l, &rt1, &rt2, &cc, &ss);
          if (lane < 16) {
            float z1 = Zt[l][lane], z0 = Zt[l - 1][lane];
            Zt[l][lane] = cc * z1 - ss * z0;
            Zt[l - 1][lane] = ss * z1 + cc * z0;
          }
          if (lane == l - 1) { dreg = rt1; ereg = 0.f; dsh = rt2; }
          if (lane == l) dreg = rt2;
          if (lane == l - 2) dsh = rt1;
          l -= 2; if (l >= lend) continue; break;
        }
        if (jtot == nmaxit) break;
        jtot++;
        float d0 = dreg, e0 = ereg;
        float pp = rl(d0, l);
        float e_lm1 = rl(e0, l - 1);
        float gg = (rl(d0, l - 1) - pp) * 0.5f * frcp(e_lm1);
        float rr = slapy2f(gg, 1.f);
        gg = rl(d0, mq) - pp + e_lm1 * frcp(gg + copysignf(rr, gg));
        float ss_ = 1.f, cc_ = 1.f;
        pp = 0.f;
        float zc = (lane < 16) ? Zt[mq][lane] : 0.f;
        float znxt = (lane < 16) ? Zt[mq + 1][lane] : 0.f;  // prefetch
        for (int i = mq; i <= l - 1; i++) {
          float z1 = znxt;
          if (i < l - 1) znxt = (lane < 16) ? Zt[i + 2][lane] : 0.f;  // prefetch next
          float e_i = rl(e0, i), d_i = rl(d0, i), d_i1 = rl(d0, i + 1);
          float ff = ss_ * e_i, bb = cc_ * e_i;
          slartgf(gg, ff, &cc_, &ss_, &rr);
          if (i != mq) { if (lane == i - 1) ereg = rr; }
          gg = d_i - pp;
          rr = (d_i1 - gg) * ss_ + 2.f * cc_ * bb;
          pp = ss_ * rr;
          float dnew = gg + pp;
          if (lane == i) dreg = dnew;
          if (lane == i - 1) dsh = dnew;
          gg = cc_ * rr - bb;
          if (lane < 16) Zt[i][lane] = ss_ * z1 + cc_ * zc;
          zc = cc_ * z1 - ss_ * zc;
        }
        if (lane < 16) Zt[l][lane] = zc;
        float dlv = rl(d0, l) - pp;
        if (lane == l) dreg = dlv;
        if (lane == l - 1) { ereg = gg; dsh = dlv; }
      }
    }
  }
  asm volatile("" ::: "memory");

  // ---- outputs ----
  float mx = rl(dreg, 0);
  int k = 0;
#pragma unroll
  for (int j = 1; j < 16; j++) {
    float dj = rl(dreg, j);
    if (dj > mx) { mx = dj; k = j; }
  }
  float ratio = mx / trace;
  float act = 1.f / (1.f + expf(-(ratio - bias[o])));
  if (lane < 16) out[512 + bo * 16 + lane] = Zt[k][lane];
  if (lane == 0) out[bo] = act;
}

extern "C" void kernel_launch(void* const* d_in, const int* in_sizes, int n_in,
                              void* d_out, int out_size, void* d_ws, size_t ws_size,
                              hipStream_t stream) {
  const float* in = (const float*)d_in[0];
  const float* w = (const float*)d_in[1];
  const float* bias = (const float*)d_in[2];
  float* out = (float*)d_out;
  float* Tmom = (float*)d_ws;  // 512 * 4 * 256 floats = 2 MB scratch

  moments_kernel<<<B_ * L_, 256, 0, stream>>>(in, Tmom);
  gram_eig_kernel<<<B_ * O_, 64, 0, stream>>>(Tmom, w, bias, out);
}

// Round 5
// 131.097 us; speedup vs baseline: 1.6448x; 1.0114x over previous
//
#include <hip/hip_runtime.h>

#define B_ 16
#define L_ 32
#define O_ 32
#define M_ 256
#define CH_ 544   // L*(P+1)

// ---------- cross-lane helpers ----------

__device__ __forceinline__ float rl(float v, int lane) {
  return __int_as_float(__builtin_amdgcn_readlane(__float_as_int(v), lane));
}

__device__ __forceinline__ float sum16_rl(float v) {
  float s = rl(v, 0);
#pragma unroll
  for (int j = 1; j < 16; j++) s += rl(v, j);
  return s;
}

__device__ __forceinline__ float frcp(float x) { return __builtin_amdgcn_rcpf(x); }
__device__ __forceinline__ float frsq(float x) { return __builtin_amdgcn_rsqf(x); }

// ---------- LAPACK helper transcriptions (f32, branchless) ----------

__device__ __forceinline__ float slapy2f(float x, float y) {
  float xa = fabsf(x), ya = fabsf(y);
  float w = fmaxf(xa, ya), z = fminf(xa, ya);
  float q = z * frcp(w);
  float res = w * sqrtf(1.f + q * q);
  return (z == 0.f) ? w : res;
}

// LAPACK >= 3.10 slartg convention; single-rsq, branchless.
__device__ __forceinline__ void slartgf(float f, float g, float* c, float* s, float* r) {
  float t = f * f + g * g;
  float inv = frsq(t);
  float d = t * inv;
  float cg = fabsf(f) * inv;
  float rg = copysignf(d, f);
  float sg = g * copysignf(inv, f);
  bool g0 = (g == 0.f), f0 = (f == 0.f);
  *c = g0 ? 1.f : (f0 ? 0.f : cg);
  *s = g0 ? 0.f : (f0 ? copysignf(1.f, g) : sg);
  *r = g0 ? f : (f0 ? fabsf(g) : rg);
}

__device__ __forceinline__ void slaev2f(float a, float b, float c,
                                        float* rt1, float* rt2, float* cs1, float* sn1) {
  float sm = a + c, df = a - c;
  float adf = fabsf(df);
  float tb = b + b;
  float ab = fabsf(tb);
  float acmx, acmn;
  if (fabsf(a) > fabsf(c)) { acmx = a; acmn = c; } else { acmx = c; acmn = a; }
  float rt;
  if (adf > ab) { float q = ab / adf; rt = adf * sqrtf(1.f + q * q); }
  else if (adf < ab) { float q = adf / ab; rt = ab * sqrtf(1.f + q * q); }
  else rt = ab * sqrtf(2.f);
  int sgn1;
  if (sm < 0.f) { *rt1 = 0.5f * (sm - rt); sgn1 = -1; *rt2 = (acmx / *rt1) * acmn - (b / *rt1) * b; }
  else if (sm > 0.f) { *rt1 = 0.5f * (sm + rt); sgn1 = 1; *rt2 = (acmx / *rt1) * acmn - (b / *rt1) * b; }
  else { *rt1 = 0.5f * rt; *rt2 = -0.5f * rt; sgn1 = 1; }
  float cs; int sgn2;
  if (df >= 0.f) { cs = df + rt; sgn2 = 1; } else { cs = df - rt; sgn2 = -1; }
  float acs = fabsf(cs), c1, s1;
  if (acs > ab) { float ct = -tb / cs; s1 = 1.f / sqrtf(1.f + ct * ct); c1 = ct * s1; }
  else if (ab == 0.f) { c1 = 1.f; s1 = 0.f; }
  else { float tn = -cs / tb; c1 = 1.f / sqrtf(1.f + tn * tn); s1 = tn * c1; }
  if (sgn1 == sgn2) { float tn = c1; c1 = -s1; s1 = tn; }
  *cs1 = c1; *sn1 = s1;
}

// ---------- Kernel 1: weighted pose second moments (single reduced copy) ----------
__global__ __launch_bounds__(256) void moments_kernel(const float* __restrict__ in,
                                                      float* __restrict__ Tmom) {
  int bl = blockIdx.x;
  int b = bl >> 5, l = bl & 31;
  int t = threadIdx.x;
  int w = t >> 6, lane = t & 63;
  __shared__ __align__(16) float ut[4][16][68];
  __shared__ float red[4][16][16];
  const float* base = in + (size_t)b * (M_ * CH_);
  const float* row = base + (size_t)(w * 64 + lane) * CH_ + l * 16;
  float4 p0 = *(const float4*)(row + 0);
  float4 p1 = *(const float4*)(row + 4);
  float4 p2 = *(const float4*)(row + 8);
  float4 p3 = *(const float4*)(row + 12);
  float a = row[512 - l * 16 + l];
  float (*u)[68] = ut[w];
  u[0][lane] = a * p0.x;  u[1][lane] = a * p0.y;  u[2][lane] = a * p0.z;  u[3][lane] = a * p0.w;
  u[4][lane] = a * p1.x;  u[5][lane] = a * p1.y;  u[6][lane] = a * p1.z;  u[7][lane] = a * p1.w;
  u[8][lane] = a * p2.x;  u[9][lane] = a * p2.y;  u[10][lane] = a * p2.z; u[11][lane] = a * p2.w;
  u[12][lane] = a * p3.x; u[13][lane] = a * p3.y; u[14][lane] = a * p3.z; u[15][lane] = a * p3.w;
  asm volatile("" ::: "memory");
  int c = lane & 15, r0 = lane >> 4;
  float acc0 = 0.f, acc1 = 0.f, acc2 = 0.f, acc3 = 0.f;
#pragma unroll
  for (int m4 = 0; m4 < 64; m4 += 4) {
    float4 cv = *(const float4*)&u[c][m4];
    float4 a0 = *(const float4*)&u[r0][m4];
    float4 a1 = *(const float4*)&u[r0 + 4][m4];
    float4 a2 = *(const float4*)&u[r0 + 8][m4];
    float4 a3 = *(const float4*)&u[r0 + 12][m4];
    acc0 += a0.x * cv.x + a0.y * cv.y + a0.z * cv.z + a0.w * cv.w;
    acc1 += a1.x * cv.x + a1.y * cv.y + a1.z * cv.z + a1.w * cv.w;
    acc2 += a2.x * cv.x + a2.y * cv.y + a2.z * cv.z + a2.w * cv.w;
    acc3 += a3.x * cv.x + a3.y * cv.y + a3.z * cv.z + a3.w * cv.w;
  }
  red[w][r0][c] = acc0;
  red[w][r0 + 4][c] = acc1;
  red[w][r0 + 8][c] = acc2;
  red[w][r0 + 12][c] = acc3;
  __syncthreads();
  int rr_ = t >> 4, cc_ = t & 15;
  float s = (red[0][rr_][cc_] + red[1][rr_][cc_]) + (red[2][rr_][cc_] + red[3][rr_][cc_]);
  Tmom[bl * 256 + t] = s;
}

// ---------- Kernel 2: gram + register-resident LAPACK-replica eigh ----------
__global__ __launch_bounds__(64) void gram_eig_kernel(const float* __restrict__ Tmom,
                                                      const float* __restrict__ Wt,
                                                      const float* __restrict__ bias,
                                                      float* __restrict__ out) {
  int bo = blockIdx.x;
  int b = bo >> 5, o = bo & 31;
  int lane = threadIdx.x;

  __shared__ __align__(16) float4 Wall4[128];
  __shared__ __align__(16) float4 Tsh4[4 * 18];
  __shared__ float A[16][17];
  __shared__ __align__(16) float Zt[16][16];

  float biasv = bias[o];

  // ---- stage W (single wave: DS in-order, no barrier) ----
  const float4* Wt4 = (const float4*)Wt;
#pragma unroll
  for (int k = 0; k < 2; k++) {
    int idx = lane + 64 * k;
    int l = idx >> 2, part = idx & 3;
    Wall4[idx] = Wt4[(l * 32 + o) * 4 + part];
  }
  asm volatile("" ::: "memory");

  // ---- gram (single-copy T, depth-4 prefetch, barrier-free) ----
  int p = lane >> 2;
  int i_ = p >> 2, k_ = p & 3;
  int i2 = lane & 3;
  float gx = 0.f, gy = 0.f, gz = 0.f, gw = 0.f;
  const float4* T4 = (const float4*)(Tmom + (size_t)(b * 32) * 256);
  const float* WallF = (const float*)Wall4;
  float4 t0 = T4[0 * 64 + lane], t1 = T4[1 * 64 + lane];
  float4 t2 = T4[2 * 64 + lane], t3 = T4[3 * 64 + lane];
  for (int l = 0; l < 32; l++) {
    Tsh4[(lane >> 4) * 18 + (lane & 15)] = t0;
    asm volatile("" ::: "memory");
    t0 = t1; t1 = t2; t2 = t3;
    if (l + 4 < 32) t3 = T4[(l + 4) * 64 + lane];
    float4 wq0 = Wall4[l * 4 + 0], wq1 = Wall4[l * 4 + 1];
    float4 wq2 = Wall4[l * 4 + 2], wq3 = Wall4[l * 4 + 3];
#pragma unroll
    for (int jj = 0; jj < 4; jj++) {
      float4 trow = Tsh4[i_ * 18 + jj * 4 + i2];
      float ux = trow.x * wq0.x + trow.y * wq1.x + trow.z * wq2.x + trow.w * wq3.x;
      float uy = trow.x * wq0.y + trow.y * wq1.y + trow.z * wq2.y + trow.w * wq3.y;
      float uz = trow.x * wq0.z + trow.y * wq1.z + trow.z * wq2.z + trow.w * wq3.z;
      float uw = trow.x * wq0.w + trow.y * wq1.w + trow.z * wq2.w + trow.w * wq3.w;
      float wk = WallF[l * 16 + jj * 4 + k_];
      gx += wk * ux; gy += wk * uy; gz += wk * uz; gw += wk * uw;
    }
    asm volatile("" ::: "memory");
  }
  {
    int q0 = i2 * 4;
    A[p][q0 + 0] = gx; A[p][q0 + 1] = gy; A[p][q0 + 2] = gz; A[p][q0 + 3] = gw;
  }
  asm volatile("" ::: "memory");

  // ---- load A columns into registers: lane c holds a[r] = A[r][c] ----
  int c16 = lane & 15;
  float a[16];
#pragma unroll
  for (int r = 0; r < 16; r++) a[r] = A[r][c16];

  float trace;
  {
    float diag = 0.f;
#pragma unroll
    for (int r = 0; r < 16; r++) if (c16 == r) diag = a[r];
    trace = sum16_rl((lane < 16) ? diag : 0.f);
  }

  // ---- ssytd2 (lower), register-resident ----
  float dreg = 0.f, ereg = 0.f, taureg = 0.f;
  float hv[14];
#pragma unroll
  for (int i = 0; i < 15; i++) {
    float cn = 0.f;
#pragma unroll
    for (int r = i + 2; r < 16; r++) cn += a[r] * a[r];
    float xn2 = rl(cn, i);
    float alpha = rl(a[i + 1], i);
    float taui = 0.f;
    float vc = 0.f;
    if (xn2 == 0.f) {
      if (lane == i) ereg = alpha;
    } else {
      float xnorm = sqrtf(xn2);
      float beta = -copysignf(slapy2f(alpha, xnorm), alpha);
      taui = (beta - alpha) / beta;
      float rs = 1.f / (alpha - beta);
      if (lane == i) ereg = beta;
      vc = (lane == i + 1) ? 1.f : ((lane >= i + 2 && lane < 16) ? a[i] * rs : 0.f);
      float vb[16];
#pragma unroll
      for (int r = i + 1; r < 16; r++) vb[r] = rl(vc, r);
      float acc = 0.f;
#pragma unroll
      for (int r = i + 1; r < 16; r++) acc += a[r] * vb[r];
      float wc = (lane >= i + 1 && lane < 16) ? taui * acc : 0.f;
      float wb[16];
#pragma unroll
      for (int r = i + 1; r < 16; r++) wb[r] = rl(wc, r);
      float dot = 0.f;
#pragma unroll
      for (int r = i + 1; r < 16; r++) dot += vb[r] * wb[r];
      float alph2 = -0.5f * taui * dot;
      wc += alph2 * vc;
#pragma unroll
      for (int r = i + 1; r < 16; r++) wb[r] += alph2 * vb[r];
#pragma unroll
      for (int r = i + 1; r < 16; r++) a[r] -= vb[r] * wc + wb[r] * vc;
    }
    if (i < 14) hv[i] = vc;
    if (lane == i) taureg = taui;
  }
#pragma unroll
  for (int r = 0; r < 16; r++) if (c16 == r) dreg = a[r];
  if (lane >= 16) dreg = 0.f;

  // ---- form Q = H(1)..H(14); lane = column, rows in registers ----
  float z[16];
#pragma unroll
  for (int r = 0; r < 16; r++) z[r] = (lane == r) ? 1.f : 0.f;
#pragma unroll
  for (int i = 13; i >= 0; i--) {
    float taui = rl(taureg, i);
    if (taui != 0.f) {
      float vbq[16];
      float s = 0.f;
#pragma unroll
      for (int r = i + 1; r < 16; r++) { vbq[r] = rl(hv[i], r); s += vbq[r] * z[r]; }
      s *= taui;
#pragma unroll
      for (int r = i + 1; r < 16; r++) z[r] -= vbq[r] * s;
    }
  }
  if (lane < 16) {
    float4* zt4 = (float4*)&Zt[lane][0];      // Zt[col][row]
    zt4[0] = make_float4(z[0], z[1], z[2], z[3]);
    zt4[1] = make_float4(z[4], z[5], z[6], z[7]);
    zt4[2] = make_float4(z[8], z[9], z[10], z[11]);
    zt4[3] = make_float4(z[12], z[13], z[14], z[15]);
  }
  asm volatile("" ::: "memory");

  // ---- transpose handoff: zz[col] = Z[lane][col], register-resident ----
  float zz[16];
#pragma unroll
  for (int k2 = 0; k2 < 16; k2++) zz[k2] = Zt[k2][c16];

  // ---- ssteqr; d,e lane-resident; Z in registers; sweeps unrolled ----
  const float eps = 5.9604645e-08f;
  const float eps2 = eps * eps;
  const float safmin = 1.17549435e-38f;
  int l1 = 0, jtot = 0;
  const int nmaxit = 480;
  float dsh = __shfl(dreg, (lane + 1) & 63, 64);

  while (l1 < 16) {
    if (l1 > 0) { if (lane == l1 - 1) ereg = 0.f; }
    bool co = (lane < 15) &&
              ((ereg == 0.f) ||
               (fabsf(ereg) <= __builtin_amdgcn_sqrtf(fabsf(dreg)) *
                                   __builtin_amdgcn_sqrtf(fabsf(dsh)) * eps));
    unsigned long long bm = __ballot(co) & ~((1ull << l1) - 1ull);
    int m = bm ? (__ffsll(bm) - 1) : 15;
    if (m < 15) { if (lane == m) ereg = 0.f; }
    int l = l1, lend = m;
    l1 = m + 1;
    if (lend == l) continue;
    {
      float dl = rl(dreg, l), dle = rl(dreg, lend);
      if (fabsf(dle) < fabsf(dl)) { int tq = l; l = lend; lend = tq; }
    }

    if (lend > l) {
      // ---- QL ----
      for (;;) {
        bool cj = (lane < 15) && ((ereg * ereg) <= eps2 * fabsf(dreg) * fabsf(dsh) + safmin);
        int mq;
        if (l != lend) {
          unsigned long long bb2 = __ballot(cj) & ((1ull << lend) - 1ull) & ~((1ull << l) - 1ull);
          mq = bb2 ? (__ffsll(bb2) - 1) : lend;
        } else mq = lend;
        if (mq < lend) { if (lane == mq) ereg = 0.f; }
        if (mq == l) { l++; if (l <= lend) continue; break; }
        if (mq == l + 1) {
          float d_l = rl(dreg, l), e_l = rl(ereg, l), d_l1 = rl(dreg, l + 1);
          float rt1, rt2, cc, ss;
          slaev2f(d_l, e_l, d_l1, &rt1, &rt2, &cc, &ss);
#pragma unroll
          for (int k = 0; k < 15; k++) if (k == l) {
            float z1 = zz[k + 1], z0v = zz[k];
            zz[k + 1] = cc * z1 - ss * z0v;
            zz[k] = ss * z1 + cc * z0v;
          }
          if (lane == l) { dreg = rt1; ereg = 0.f; dsh = rt2; }
          if (lane == l + 1) dreg = rt2;
          if (lane == l - 1) dsh = rt1;
          l += 2; if (l <= lend) continue; break;
        }
        if (jtot == nmaxit) break;
        jtot++;
        float d0 = dreg, e0 = ereg;   // pre-sweep snapshots
        float pp = rl(d0, l);
        float e_lv = rl(e0, l);
        float gg = (rl(d0, l + 1) - pp) * 0.5f * frcp(e_lv);
        float rr = slapy2f(gg, 1.f);
        gg = rl(d0, mq) - pp + e_lv * frcp(gg + copysignf(rr, gg));
        float ss_ = 1.f, cc_ = 1.f;
        pp = 0.f;
#pragma unroll
        for (int i = 14; i >= 0; i--) {
          if (i <= mq - 1 && i >= l) {   // wave-uniform guard; i is compile-time
            float e_i = rl(e0, i), d_i = rl(d0, i), d_i1 = rl(d0, i + 1);
            float ff = ss_ * e_i, bb = cc_ * e_i;
            slartgf(gg, ff, &cc_, &ss_, &rr);
            if (i != mq - 1) { if (lane == i + 1) ereg = rr; }
            gg = d_i1 - pp;
            rr = (d_i - gg) * ss_ + 2.f * cc_ * bb;
            pp = ss_ * rr;
            float dnew = gg + pp;
            if (lane == i + 1) dreg = dnew;
            if (lane == i) dsh = dnew;
            gg = cc_ * rr - bb;
            float z1 = zz[i + 1], z0v = zz[i];   // QL (slasr 'B', (c,-s))
            zz[i + 1] = cc_ * z1 + ss_ * z0v;
            zz[i] = -ss_ * z1 + cc_ * z0v;
          }
        }
        float dlv = rl(d0, l) - pp;
        if (lane == l) { dreg = dlv; ereg = gg; }
        if (lane == l - 1) dsh = dlv;
      }
    } else {
      // ---- QR ----
      for (;;) {
        bool cj = (lane < 15) && ((ereg * ereg) <= eps2 * fabsf(dreg) * fabsf(dsh) + safmin);
        int mq;
        if (l != lend) {
          unsigned long long bb2 = __ballot(cj) & ((1ull << l) - 1ull) & ~((1ull << lend) - 1ull);
          mq = bb2 ? (63 - __clzll(bb2) + 1) : lend;
        } else mq = lend;
        if (mq > lend) { if (lane == mq - 1) ereg = 0.f; }
        if (mq == l) { l--; if (l >= lend) continue; break; }
        if (mq == l - 1) {
          float d_lm1 = rl(dreg, l - 1), e_lm1 = rl(ereg, l - 1), d_l = rl(dreg, l);
          float rt1, rt2, cc, ss;
          slaev2f(d_lm1, e_lm1, d_l, &rt1, &rt2, &cc, &ss);
#pragma unroll
          for (int k = 0; k < 15; k++) if (k == l - 1) {
            float z1 = zz[k + 1], z0v = zz[k];
            zz[k + 1] = cc * z1 - ss * z0v;
            zz[k] = ss * z1 + cc * z0v;
          }
          if (lane == l - 1) { dreg = rt1; ereg = 0.f; dsh = rt2; }
          if (lane == l) dreg = rt2;
          if (lane == l - 2) dsh = rt1;
          l -= 2; if (l >= lend) continue; break;
        }
        if (jtot == nmaxit) break;
        jtot++;
        float d0 = dreg, e0 = ereg;
        float pp = rl(d0, l);
        float e_lm1 = rl(e0, l - 1);
        float gg = (rl(d0, l - 1) - pp) * 0.5f * frcp(e_lm1);
        float rr = slapy2f(gg, 1.f);
        gg = rl(d0, mq) - pp + e_lm1 * frcp(gg + copysignf(rr, gg));
        float ss_ = 1.f, cc_ = 1.f;
        pp = 0.f;
#pragma unroll
        for (int i = 0; i <= 14; i++) {
          if (i >= mq && i <= l - 1) {   // wave-uniform guard; i is compile-time
            float e_i = rl(e0, i), d_i = rl(d0, i), d_i1 = rl(d0, i + 1);
            float ff = ss_ * e_i, bb = cc_ * e_i;
            slartgf(gg, ff, &cc_, &ss_, &rr);
            if (i != mq) { if (lane == i - 1) ereg = rr; }
            gg = d_i - pp;
            rr = (d_i1 - gg) * ss_ + 2.f * cc_ * bb;
            pp = ss_ * rr;
            float dnew = gg + pp;
            if (lane == i) dreg = dnew;
            if (lane == i - 1) dsh = dnew;
            gg = cc_ * rr - bb;
            float z1 = zz[i + 1], z0v = zz[i];   // QR (slasr 'F', (c,s))
            zz[i + 1] = cc_ * z1 - ss_ * z0v;
            zz[i] = ss_ * z1 + cc_ * z0v;
          }
        }
        float dlv = rl(d0, l) - pp;
        if (lane == l) dreg = dlv;
        if (lane == l - 1) { ereg = gg; dsh = dlv; }
      }
    }
  }

  // ---- outputs ----
  float mx = rl(dreg, 0);
  int k = 0;
#pragma unroll
  for (int j = 1; j < 16; j++) {
    float dj = rl(dreg, j);
    if (dj > mx) { mx = dj; k = j; }
  }
  float ratio = mx / trace;
  float act = 1.f / (1.f + expf(-(ratio - biasv)));
  float zk = zz[0];
#pragma unroll
  for (int j = 1; j < 16; j++) zk = (k == j) ? zz[j] : zk;
  if (lane < 16) out[512 + bo * 16 + lane] = zk;
  if (lane == 0) out[bo] = act;
}

extern "C" void kernel_launch(void* const* d_in, const int* in_sizes, int n_in,
                              void* d_out, int out_size, void* d_ws, size_t ws_size,
                              hipStream_t stream) {
  const float* in = (const float*)d_in[0];
  const float* w = (const float*)d_in[1];
  const float* bias = (const float*)d_in[2];
  float* out = (float*)d_out;
  float* Tmom = (float*)d_ws;  // 512 * 256 floats = 512 KB scratch

  moments_kernel<<<B_ * L_, 256, 0, stream>>>(in, Tmom);
  gram_eig_kernel<<<B_ * O_, 64, 0, stream>>>(Tmom, w, bias, out);
}